// Round 1
// baseline (178.756 us; speedup 1.0000x reference)
//
#include <hip/hip_runtime.h>
#include <cstdint>
#include <cstddef>

typedef short bf16x8 __attribute__((ext_vector_type(8)));
typedef float f32x4 __attribute__((ext_vector_type(4)));

#define HH 48
#define WW 64
#define HWSZ 3072
#define SCALE_Q 0.08838834764831845f

__device__ __forceinline__ float b2f(unsigned short u) {
    union { unsigned int i; float f; } c; c.i = ((unsigned int)u) << 16; return c.f;
}
__device__ __forceinline__ unsigned short f2b(float f) {
    union { float f; unsigned int i; } c; c.f = f;
    unsigned int r = (c.i + 0x7fffu + ((c.i >> 16) & 1u)) >> 16;
    return (unsigned short)r;
}

// ---------------- K0a: fmap (fb, c, pos) f32 -> Xb (fb, pos, c) bf16 ----------------
__global__ __launch_bounds__(256) void k_transpose(const float* __restrict__ f0,
                                                   const float* __restrict__ f1,
                                                   unsigned short* __restrict__ Xb) {
    __shared__ float t[32][33];
    int fb = blockIdx.z; int f = fb >> 1, bb = fb & 1;
    const float* src = f ? f1 : f0;
    int pT = blockIdx.x * 32, cT = blockIdx.y * 32;
    int tx = threadIdx.x, ty = threadIdx.y;
#pragma unroll
    for (int i = 0; i < 4; ++i) {
        int c = cT + ty + i * 8, pos = pT + tx;
        t[ty + i * 8][tx] = src[(size_t)(bb * 128 + c) * HWSZ + pos];
    }
    __syncthreads();
#pragma unroll
    for (int i = 0; i < 4; ++i) {
        int pos = pT + ty + i * 8, c = cT + tx;
        Xb[(size_t)(fb * HWSZ + pos) * 128 + c] = f2b(t[tx][ty + i * 8]);
    }
}

// ---------------- K0b: weights -> bf16. Wcat[o][c] (o<512: SCALE*Wqk rows; else Wv), Wpb[c][o] ----------------
__global__ __launch_bounds__(256) void k_weights(const float* __restrict__ Wqk,
                                                 const float* __restrict__ Wv,
                                                 const float* __restrict__ Wp,
                                                 unsigned short* __restrict__ Wcat,
                                                 unsigned short* __restrict__ Wpb) {
    int idx = blockIdx.x * 256 + threadIdx.x;
    if (idx < 131072) {
        int o = idx >> 7, c = idx & 127;
        float v = (o < 512) ? Wqk[o * 128 + c] * SCALE_Q : Wv[(o - 512) * 128 + c];
        Wcat[idx] = f2b(v);
    } else {
        int j = idx - 131072;
        Wpb[j] = f2b(Wp[j]);
    }
}

// ---------------- K1: C[pos,o] = Xb[pos,:]*Wcat[o,:]; q -> Qx[f,x,(b,n,y),d], v -> Vt[fbn,d,key] ----------------
__global__ __launch_bounds__(256) void k_qv(const unsigned short* __restrict__ Xb,
                                            const unsigned short* __restrict__ Wcat,
                                            unsigned short* __restrict__ Qx,
                                            unsigned short* __restrict__ Vt) {
    __shared__ unsigned short Asub[64 * 136];
    __shared__ unsigned short Bsub[128 * 136];
    int mt = blockIdx.x, nt = blockIdx.y, fb = blockIdx.z;
    int tid = threadIdx.x;
    const unsigned short* asrc = Xb + (size_t)(fb * HWSZ + mt * 64) * 128;
    const unsigned short* bsrc = Wcat + (size_t)nt * 128 * 128;
    for (int ch = tid; ch < 1024; ch += 256) {
        int row = ch >> 4, seg = ch & 15;
        *(bf16x8*)&Asub[row * 136 + seg * 8] = *(const bf16x8*)(asrc + ch * 8);
    }
    for (int ch = tid; ch < 2048; ch += 256) {
        int row = ch >> 4, seg = ch & 15;
        *(bf16x8*)&Bsub[row * 136 + seg * 8] = *(const bf16x8*)(bsrc + ch * 8);
    }
    __syncthreads();
    int l = tid & 63, w = tid >> 6;
    int wm = w >> 1, wn = w & 1;
    int lr = l & 15, lk8 = (l >> 4) * 8;
    f32x4 acc[2][4] = {};
#pragma unroll
    for (int kt = 0; kt < 4; ++kt) {
        bf16x8 a[2], b[4];
#pragma unroll
        for (int m = 0; m < 2; ++m)
            a[m] = *(const bf16x8*)&Asub[(wm * 32 + m * 16 + lr) * 136 + kt * 32 + lk8];
#pragma unroll
        for (int n = 0; n < 4; ++n)
            b[n] = *(const bf16x8*)&Bsub[(wn * 64 + n * 16 + lr) * 136 + kt * 32 + lk8];
#pragma unroll
        for (int m = 0; m < 2; ++m)
#pragma unroll
            for (int n = 0; n < 4; ++n)
                acc[m][n] = __builtin_amdgcn_mfma_f32_16x16x32_bf16(a[m], b[n], acc[m][n], 0, 0, 0);
    }
    int f = fb >> 1, bb = fb & 1;
#pragma unroll
    for (int m = 0; m < 2; ++m)
#pragma unroll
        for (int n = 0; n < 4; ++n) {
            int o = nt * 128 + wn * 64 + n * 16 + lr;
            int pos0 = mt * 64 + wm * 32 + m * 16 + (l >> 4) * 4;
            if (o < 512) {
                int nh = o >> 7, d = o & 127;
#pragma unroll
                for (int r = 0; r < 4; ++r) {
                    int pos = pos0 + r, x = pos >> 6, y = pos & 63;
                    Qx[(size_t)((f * 48 + x) * 512 + (bb * 4 + nh) * 64 + y) * 128 + d] = f2b(acc[m][n][r]);
                }
            } else {
                int oo = o - 512, nh = oo >> 7, d = oo & 127;
                uint2 val;
                val.x = (unsigned int)f2b(acc[m][n][0]) | ((unsigned int)f2b(acc[m][n][1]) << 16);
                val.y = (unsigned int)f2b(acc[m][n][2]) | ((unsigned int)f2b(acc[m][n][3]) << 16);
                *(uint2*)&Vt[(size_t)((fb * 4 + nh) * 128 + d) * HWSZ + pos0] = val;
            }
        }
}

// ---------------- K2a: hs = q . He, softmax over u (48) -> PH[f,x,row,48] bf16 ----------------
__global__ __launch_bounds__(256) void k_ph(const unsigned short* __restrict__ Qx,
                                            const float* __restrict__ rel_h,
                                            unsigned short* __restrict__ PH) {
    __shared__ float sm[4][16][52];
    int x = blockIdx.x, f = blockIdx.y;
    int tid = threadIdx.x, l = tid & 63, w = tid >> 6;
    int lr = l & 15, lk8 = (l >> 4) * 8;
    bf16x8 bh[3][4];
#pragma unroll
    for (int ut = 0; ut < 3; ++ut) {
        int u = ut * 16 + lr, rr = x - u + 99;
#pragma unroll
        for (int kt = 0; kt < 4; ++kt) {
            const float* s = rel_h + rr * 128 + kt * 32 + lk8;
            float4 a0 = *(const float4*)s, a1 = *(const float4*)(s + 4);
            bf16x8 pk;
            pk[0] = (short)f2b(a0.x); pk[1] = (short)f2b(a0.y); pk[2] = (short)f2b(a0.z); pk[3] = (short)f2b(a0.w);
            pk[4] = (short)f2b(a1.x); pk[5] = (short)f2b(a1.y); pk[6] = (short)f2b(a1.z); pk[7] = (short)f2b(a1.w);
            bh[ut][kt] = pk;
        }
    }
    const unsigned short* qbase = Qx + (size_t)(f * 48 + x) * 512 * 128;
    unsigned short* phbase = PH + (size_t)(f * 48 + x) * 512 * 48;
    for (int mt = 0; mt < 8; ++mt) {
        int rg = w * 128 + mt * 16 + lr;
        const unsigned short* qrow = qbase + (size_t)rg * 128;
        bf16x8 a[4];
#pragma unroll
        for (int kt = 0; kt < 4; ++kt) a[kt] = *(const bf16x8*)(qrow + kt * 32 + lk8);
        f32x4 acc[3] = {};
#pragma unroll
        for (int kt = 0; kt < 4; ++kt)
#pragma unroll
            for (int ut = 0; ut < 3; ++ut)
                acc[ut] = __builtin_amdgcn_mfma_f32_16x16x32_bf16(a[kt], bh[ut][kt], acc[ut], 0, 0, 0);
        __syncthreads();
#pragma unroll
        for (int ut = 0; ut < 3; ++ut)
#pragma unroll
            for (int r = 0; r < 4; ++r)
                sm[w][(l >> 4) * 4 + r][ut * 16 + lr] = acc[ut][r];
        __syncthreads();
        int part = l >> 4;
        float vb[12];
        float mx = -1e30f;
#pragma unroll
        for (int j = 0; j < 12; ++j) { vb[j] = sm[w][lr][part * 12 + j]; mx = fmaxf(mx, vb[j]); }
        mx = fmaxf(mx, __shfl_xor(mx, 16, 64));
        mx = fmaxf(mx, __shfl_xor(mx, 32, 64));
        float ssum = 0.f;
#pragma unroll
        for (int j = 0; j < 12; ++j) { vb[j] = __expf(vb[j] - mx); ssum += vb[j]; }
        ssum += __shfl_xor(ssum, 16, 64);
        ssum += __shfl_xor(ssum, 32, 64);
        float inv = 1.0f / ssum;
        unsigned short* dst = phbase + (size_t)(w * 128 + mt * 16 + lr) * 48 + part * 12;
#pragma unroll
        for (int j = 0; j < 12; ++j) dst[j] = f2b(vb[j] * inv);
    }
}

// ---------------- K2b: ws = q . We, softmax over v (64) -> PW[f,y,row,64] bf16 ----------------
__global__ __launch_bounds__(256) void k_pw(const unsigned short* __restrict__ Qx,
                                            const float* __restrict__ rel_w,
                                            unsigned short* __restrict__ PW) {
    __shared__ float sm[4][16][68];
    int y = blockIdx.x, f = blockIdx.y;
    int tid = threadIdx.x, l = tid & 63, w = tid >> 6;
    int lr = l & 15, lk8 = (l >> 4) * 8;
    bf16x8 bw[4][4];
#pragma unroll
    for (int vt = 0; vt < 4; ++vt) {
        int v = vt * 16 + lr, rr = y - v + 99;
#pragma unroll
        for (int kt = 0; kt < 4; ++kt) {
            const float* s = rel_w + rr * 128 + kt * 32 + lk8;
            float4 a0 = *(const float4*)s, a1 = *(const float4*)(s + 4);
            bf16x8 pk;
            pk[0] = (short)f2b(a0.x); pk[1] = (short)f2b(a0.y); pk[2] = (short)f2b(a0.z); pk[3] = (short)f2b(a0.w);
            pk[4] = (short)f2b(a1.x); pk[5] = (short)f2b(a1.y); pk[6] = (short)f2b(a1.z); pk[7] = (short)f2b(a1.w);
            bw[vt][kt] = pk;
        }
    }
    for (int mt = 0; mt < 6; ++mt) {
        int rg = w * 96 + mt * 16 + lr;
        int bn = rg / 48, xx = rg - bn * 48;
        const unsigned short* qrow = Qx + (size_t)((f * 48 + xx) * 512 + bn * 64 + y) * 128;
        bf16x8 a[4];
#pragma unroll
        for (int kt = 0; kt < 4; ++kt) a[kt] = *(const bf16x8*)(qrow + kt * 32 + lk8);
        f32x4 acc[4] = {};
#pragma unroll
        for (int kt = 0; kt < 4; ++kt)
#pragma unroll
            for (int vt = 0; vt < 4; ++vt)
                acc[vt] = __builtin_amdgcn_mfma_f32_16x16x32_bf16(a[kt], bw[vt][kt], acc[vt], 0, 0, 0);
        __syncthreads();
#pragma unroll
        for (int vt = 0; vt < 4; ++vt)
#pragma unroll
            for (int r = 0; r < 4; ++r)
                sm[w][(l >> 4) * 4 + r][vt * 16 + lr] = acc[vt][r];
        __syncthreads();
        int part = l >> 4;
        float vb[16];
        float mx = -1e30f;
#pragma unroll
        for (int j = 0; j < 16; ++j) { vb[j] = sm[w][lr][part * 16 + j]; mx = fmaxf(mx, vb[j]); }
        mx = fmaxf(mx, __shfl_xor(mx, 16, 64));
        mx = fmaxf(mx, __shfl_xor(mx, 32, 64));
        float ssum = 0.f;
#pragma unroll
        for (int j = 0; j < 16; ++j) { vb[j] = __expf(vb[j] - mx); ssum += vb[j]; }
        ssum += __shfl_xor(ssum, 16, 64);
        ssum += __shfl_xor(ssum, 32, 64);
        float inv = 1.0f / ssum;
        unsigned short* dst = PW + (size_t)((f * 64 + y) * 384 + rg) * 64 + part * 16;
#pragma unroll
        for (int j = 0; j < 16; ++j) dst[j] = f2b(vb[j] * inv);
    }
}

// ---------------- K3: out[q,d] = sum_{u,v} ph[q,u] pw[q,v] V[u*64+v, d]  (per f,b,n) ----------------
__global__ __launch_bounds__(256) void k_attn(const unsigned short* __restrict__ PH,
                                              const unsigned short* __restrict__ PW,
                                              const unsigned short* __restrict__ Vt,
                                              unsigned short* __restrict__ AO) {
    __shared__ unsigned short phl[128 * 52];
    __shared__ unsigned short pwl[128 * 72];
    __shared__ unsigned short vtl[2][128 * 40];
    int t = blockIdx.x, fbn = blockIdx.y;
    int f = fbn >> 3, bidx = (fbn >> 2) & 1, nh = fbn & 3;
    int fb = f * 2 + bidx, bn = bidx * 4 + nh;
    int tid = threadIdx.x;
    // load ph (128 rows x 48) -> [r][52]
    for (int idx = tid; idx < 3072; idx += 256) {
        int r = idx / 24, c2 = (idx % 24) * 2;
        int x = t * 2 + (r >> 6), y = r & 63;
        const unsigned short* s = PH + (size_t)((f * 48 + x) * 512 + bn * 64 + y) * 48 + c2;
        *(unsigned int*)&phl[r * 52 + c2] = *(const unsigned int*)s;
    }
    // load pw (128 rows x 64) -> [r][72]
    for (int idx = tid; idx < 2048; idx += 256) {
        int r = idx >> 4, s4 = (idx & 15) * 4;
        int x = t * 2 + (r >> 6), y = r & 63;
        const unsigned short* s = PW + (size_t)((f * 64 + y) * 384 + bn * 48 + x) * 64 + s4;
        *(uint2*)&pwl[r * 72 + s4] = *(const uint2*)s;
    }
    const unsigned short* vsrc = Vt + (size_t)(fb * 4 + nh) * 128 * HWSZ;
    // stage tile 0
    for (int ch = tid; ch < 512; ch += 256) {
        int d = ch >> 2, seg = ch & 3;
        *(bf16x8*)&vtl[0][d * 40 + seg * 8] = *(const bf16x8*)(vsrc + (size_t)d * HWSZ + seg * 8);
    }
    __syncthreads();
    int l = tid & 63, w = tid >> 6;
    int wm = w >> 1, wn = w & 1;
    int lr = l & 15, lk8 = (l >> 4) * 8;
    int d0 = tid >> 2, g0 = (tid & 3) * 8;
    int d1 = d0 + 64;
    f32x4 acc[4][4] = {};
    for (int kt = 0; kt < 96; ++kt) {
        int cur = kt & 1;
        bf16x8 s0, s1;
        if (kt < 95) {
            const unsigned short* p = vsrc + (kt + 1) * 32;
            s0 = *(const bf16x8*)(p + (size_t)d0 * HWSZ + g0);
            s1 = *(const bf16x8*)(p + (size_t)d1 * HWSZ + g0);
        }
        int u = kt >> 1;
        int v0 = ((kt & 1) << 5) + lk8;
        bf16x8 a[4];
#pragma unroll
        for (int m = 0; m < 4; ++m) {
            int r = wm * 64 + m * 16 + lr;
            float p = b2f(phl[r * 52 + u]);
            bf16x8 wv = *(const bf16x8*)&pwl[r * 72 + v0];
#pragma unroll
            for (int j = 0; j < 8; ++j)
                a[m][j] = (short)f2b(p * b2f((unsigned short)wv[j]));
        }
        bf16x8 bv[4];
#pragma unroll
        for (int n = 0; n < 4; ++n)
            bv[n] = *(const bf16x8*)&vtl[cur][(wn * 64 + n * 16 + lr) * 40 + lk8];
#pragma unroll
        for (int m = 0; m < 4; ++m)
#pragma unroll
            for (int n = 0; n < 4; ++n)
                acc[m][n] = __builtin_amdgcn_mfma_f32_16x16x32_bf16(a[m], bv[n], acc[m][n], 0, 0, 0);
        if (kt < 95) {
            __syncthreads();
            *(bf16x8*)&vtl[cur ^ 1][d0 * 40 + g0] = s0;
            *(bf16x8*)&vtl[cur ^ 1][d1 * 40 + g0] = s1;
            __syncthreads();
        }
    }
    unsigned short* aobase = AO + (size_t)fb * HWSZ * 512 + nh * 128;
#pragma unroll
    for (int m = 0; m < 4; ++m)
#pragma unroll
        for (int n = 0; n < 4; ++n) {
            int dcol = wn * 64 + n * 16 + lr;
            int r0 = wm * 64 + m * 16 + (l >> 4) * 4;
#pragma unroll
            for (int r = 0; r < 4; ++r) {
                int xy = t * 128 + r0 + r;
                aobase[(size_t)xy * 512 + dcol] = f2b(acc[m][n][r]);
            }
        }
}

// ---------------- K4: out = fmap + gamma * (AO @ Wp^T), transposed store ----------------
__global__ __launch_bounds__(256) void k_proj(const unsigned short* __restrict__ AO,
                                              const unsigned short* __restrict__ Wpb,
                                              const float* __restrict__ f0,
                                              const float* __restrict__ f1,
                                              const float* __restrict__ gamma,
                                              float* __restrict__ out) {
    __shared__ unsigned short Asub[64 * 136];
    __shared__ unsigned short Bsub[128 * 136];
    int t = blockIdx.x, fb = blockIdx.y;
    int f = fb >> 1, bb = fb & 1;
    int tid = threadIdx.x;
    int l = tid & 63, w = tid >> 6;
    int wm = w >> 1, wn = w & 1;
    int lr = l & 15, lk8 = (l >> 4) * 8;
    f32x4 acc[2][4] = {};
    for (int ks = 0; ks < 4; ++ks) {
        if (ks) __syncthreads();
        for (int ch = tid; ch < 1024; ch += 256) {
            int row = ch >> 4, seg = ch & 15;
            *(bf16x8*)&Asub[row * 136 + seg * 8] =
                *(const bf16x8*)(AO + (size_t)(fb * HWSZ + t * 64 + row) * 512 + ks * 128 + seg * 8);
        }
        for (int ch = tid; ch < 2048; ch += 256) {
            int row = ch >> 4, seg = ch & 15;
            *(bf16x8*)&Bsub[row * 136 + seg * 8] =
                *(const bf16x8*)(Wpb + (size_t)row * 512 + ks * 128 + seg * 8);
        }
        __syncthreads();
#pragma unroll
        for (int kt = 0; kt < 4; ++kt) {
            bf16x8 a[2], b[4];
#pragma unroll
            for (int m = 0; m < 2; ++m)
                a[m] = *(const bf16x8*)&Asub[(wm * 32 + m * 16 + lr) * 136 + kt * 32 + lk8];
#pragma unroll
            for (int n = 0; n < 4; ++n)
                b[n] = *(const bf16x8*)&Bsub[(wn * 64 + n * 16 + lr) * 136 + kt * 32 + lk8];
#pragma unroll
            for (int m = 0; m < 2; ++m)
#pragma unroll
                for (int n = 0; n < 4; ++n)
                    acc[m][n] = __builtin_amdgcn_mfma_f32_16x16x32_bf16(a[m], b[n], acc[m][n], 0, 0, 0);
        }
    }
    const float* fmapf = f ? f1 : f0;
    float g = gamma[0];
#pragma unroll
    for (int m = 0; m < 2; ++m)
#pragma unroll
        for (int n = 0; n < 4; ++n) {
            int c = wn * 64 + n * 16 + lr;
            int pos0 = t * 64 + wm * 32 + m * 16 + (l >> 4) * 4;
            size_t addr = (size_t)(bb * 128 + c) * HWSZ + pos0;
            float4 fv = *(const float4*)(fmapf + addr);
            float4 ov;
            ov.x = fv.x + g * acc[m][n][0];
            ov.y = fv.y + g * acc[m][n][1];
            ov.z = fv.z + g * acc[m][n][2];
            ov.w = fv.w + g * acc[m][n][3];
            *(float4*)(out + (size_t)f * 786432 + addr) = ov;
        }
}

extern "C" void kernel_launch(void* const* d_in, const int* in_sizes, int n_in,
                              void* d_out, int out_size, void* d_ws, size_t ws_size,
                              hipStream_t stream) {
    (void)in_sizes; (void)n_in; (void)out_size; (void)ws_size;
    const float* fmap1 = (const float*)d_in[0];
    const float* fmap2 = (const float*)d_in[1];
    const float* Wqk   = (const float*)d_in[2];
    const float* Wv    = (const float*)d_in[3];
    const float* rel_h = (const float*)d_in[4];
    const float* rel_w = (const float*)d_in[5];
    const float* Wp    = (const float*)d_in[6];
    const float* gamma = (const float*)d_in[7];
    float* out = (float*)d_out;
    char* ws = (char*)d_ws;

    unsigned short* Xb   = (unsigned short*)(ws + 0);          //  3,145,728 B
    unsigned short* Wcat = (unsigned short*)(ws + 3145728);    //    262,144 B
    unsigned short* Wpb  = (unsigned short*)(ws + 3407872);    //    131,072 B
    unsigned short* Qx   = (unsigned short*)(ws + 3538944);    // 12,582,912 B
    unsigned short* AO   = Qx;                                  // alias: Qx dead after K2
    unsigned short* Vt   = (unsigned short*)(ws + 16121856);   // 12,582,912 B
    unsigned short* PH   = (unsigned short*)(ws + 28704768);   //  4,718,592 B
    unsigned short* PW   = (unsigned short*)(ws + 33423360);   //  6,291,456 B  (end 39,714,816)

    k_transpose<<<dim3(96, 4, 4), dim3(32, 8), 0, stream>>>(fmap1, fmap2, Xb);
    k_weights<<<dim3(768), dim3(256), 0, stream>>>(Wqk, Wv, Wp, Wcat, Wpb);
    k_qv<<<dim3(48, 8, 4), dim3(256), 0, stream>>>(Xb, Wcat, Qx, Vt);
    k_ph<<<dim3(48, 2), dim3(256), 0, stream>>>(Qx, rel_h, PH);
    k_pw<<<dim3(64, 2), dim3(256), 0, stream>>>(Qx, rel_w, PW);
    k_attn<<<dim3(24, 16), dim3(256), 0, stream>>>(PH, PW, Vt, AO);
    k_proj<<<dim3(48, 4), dim3(256), 0, stream>>>(AO, Wpb, fmap1, fmap2, gamma, out);
}

// Round 2
// 171.341 us; speedup vs baseline: 1.0433x; 1.0433x over previous
//
#include <hip/hip_runtime.h>
#include <cstdint>
#include <cstddef>

typedef short bf16x8 __attribute__((ext_vector_type(8)));
typedef float f32x4 __attribute__((ext_vector_type(4)));

#define HH 48
#define WW 64
#define HWSZ 3072
#define SCALE_Q 0.08838834764831845f

__device__ __forceinline__ float b2f(unsigned short u) {
    union { unsigned int i; float f; } c; c.i = ((unsigned int)u) << 16; return c.f;
}
__device__ __forceinline__ unsigned short f2b(float f) {
    union { float f; unsigned int i; } c; c.f = f;
    unsigned int r = (c.i + 0x7fffu + ((c.i >> 16) & 1u)) >> 16;
    return (unsigned short)r;
}

// ---------------- K0a: fmap (fb, c, pos) f32 -> Xb (fb, pos, c) bf16 ----------------
__global__ __launch_bounds__(256) void k_transpose(const float* __restrict__ f0,
                                                   const float* __restrict__ f1,
                                                   unsigned short* __restrict__ Xb) {
    __shared__ float t[32][33];
    int fb = blockIdx.z; int f = fb >> 1, bb = fb & 1;
    const float* src = f ? f1 : f0;
    int pT = blockIdx.x * 32, cT = blockIdx.y * 32;
    int tx = threadIdx.x, ty = threadIdx.y;
#pragma unroll
    for (int i = 0; i < 4; ++i) {
        int c = cT + ty + i * 8, pos = pT + tx;
        t[ty + i * 8][tx] = src[(size_t)(bb * 128 + c) * HWSZ + pos];
    }
    __syncthreads();
#pragma unroll
    for (int i = 0; i < 4; ++i) {
        int pos = pT + ty + i * 8, c = cT + tx;
        Xb[(size_t)(fb * HWSZ + pos) * 128 + c] = f2b(t[tx][ty + i * 8]);
    }
}

// ---------------- K0b: weights -> bf16 ----------------
__global__ __launch_bounds__(256) void k_weights(const float* __restrict__ Wqk,
                                                 const float* __restrict__ Wv,
                                                 const float* __restrict__ Wp,
                                                 unsigned short* __restrict__ Wcat,
                                                 unsigned short* __restrict__ Wpb) {
    int idx = blockIdx.x * 256 + threadIdx.x;
    if (idx < 131072) {
        int o = idx >> 7, c = idx & 127;
        float v = (o < 512) ? Wqk[o * 128 + c] * SCALE_Q : Wv[(o - 512) * 128 + c];
        Wcat[idx] = f2b(v);
    } else {
        int j = idx - 131072;
        Wpb[j] = f2b(Wp[j]);
    }
}

// ---------------- K1: q/v projections ----------------
__global__ __launch_bounds__(256) void k_qv(const unsigned short* __restrict__ Xb,
                                            const unsigned short* __restrict__ Wcat,
                                            unsigned short* __restrict__ Qx,
                                            unsigned short* __restrict__ Vt) {
    __shared__ unsigned short Asub[64 * 136];
    __shared__ unsigned short Bsub[128 * 136];
    int mt = blockIdx.x, nt = blockIdx.y, fb = blockIdx.z;
    int tid = threadIdx.x;
    const unsigned short* asrc = Xb + (size_t)(fb * HWSZ + mt * 64) * 128;
    const unsigned short* bsrc = Wcat + (size_t)nt * 128 * 128;
    for (int ch = tid; ch < 1024; ch += 256) {
        int row = ch >> 4, seg = ch & 15;
        *(bf16x8*)&Asub[row * 136 + seg * 8] = *(const bf16x8*)(asrc + ch * 8);
    }
    for (int ch = tid; ch < 2048; ch += 256) {
        int row = ch >> 4, seg = ch & 15;
        *(bf16x8*)&Bsub[row * 136 + seg * 8] = *(const bf16x8*)(bsrc + ch * 8);
    }
    __syncthreads();
    int l = tid & 63, w = tid >> 6;
    int wm = w >> 1, wn = w & 1;
    int lr = l & 15, lk8 = (l >> 4) * 8;
    f32x4 acc[2][4] = {};
#pragma unroll
    for (int kt = 0; kt < 4; ++kt) {
        bf16x8 a[2], b[4];
#pragma unroll
        for (int m = 0; m < 2; ++m)
            a[m] = *(const bf16x8*)&Asub[(wm * 32 + m * 16 + lr) * 136 + kt * 32 + lk8];
#pragma unroll
        for (int n = 0; n < 4; ++n)
            b[n] = *(const bf16x8*)&Bsub[(wn * 64 + n * 16 + lr) * 136 + kt * 32 + lk8];
#pragma unroll
        for (int m = 0; m < 2; ++m)
#pragma unroll
            for (int n = 0; n < 4; ++n)
                acc[m][n] = __builtin_amdgcn_mfma_f32_16x16x32_bf16(a[m], b[n], acc[m][n], 0, 0, 0);
    }
    int f = fb >> 1, bb = fb & 1;
#pragma unroll
    for (int m = 0; m < 2; ++m)
#pragma unroll
        for (int n = 0; n < 4; ++n) {
            int o = nt * 128 + wn * 64 + n * 16 + lr;
            int pos0 = mt * 64 + wm * 32 + m * 16 + (l >> 4) * 4;
            if (o < 512) {
                int nh = o >> 7, d = o & 127;
#pragma unroll
                for (int r = 0; r < 4; ++r) {
                    int pos = pos0 + r, x = pos >> 6, y = pos & 63;
                    Qx[(size_t)((f * 48 + x) * 512 + (bb * 4 + nh) * 64 + y) * 128 + d] = f2b(acc[m][n][r]);
                }
            } else {
                int oo = o - 512, nh = oo >> 7, d = oo & 127;
                uint2 val;
                val.x = (unsigned int)f2b(acc[m][n][0]) | ((unsigned int)f2b(acc[m][n][1]) << 16);
                val.y = (unsigned int)f2b(acc[m][n][2]) | ((unsigned int)f2b(acc[m][n][3]) << 16);
                *(uint2*)&Vt[(size_t)((fb * 4 + nh) * 128 + d) * HWSZ + pos0] = val;
            }
        }
}

// ---------------- K2a: ph softmax over u ----------------
__global__ __launch_bounds__(256) void k_ph(const unsigned short* __restrict__ Qx,
                                            const float* __restrict__ rel_h,
                                            unsigned short* __restrict__ PH) {
    __shared__ float sm[4][16][52];
    int x = blockIdx.x, f = blockIdx.y;
    int tid = threadIdx.x, l = tid & 63, w = tid >> 6;
    int lr = l & 15, lk8 = (l >> 4) * 8;
    bf16x8 bh[3][4];
#pragma unroll
    for (int ut = 0; ut < 3; ++ut) {
        int u = ut * 16 + lr, rr = x - u + 99;
#pragma unroll
        for (int kt = 0; kt < 4; ++kt) {
            const float* s = rel_h + rr * 128 + kt * 32 + lk8;
            float4 a0 = *(const float4*)s, a1 = *(const float4*)(s + 4);
            bf16x8 pk;
            pk[0] = (short)f2b(a0.x); pk[1] = (short)f2b(a0.y); pk[2] = (short)f2b(a0.z); pk[3] = (short)f2b(a0.w);
            pk[4] = (short)f2b(a1.x); pk[5] = (short)f2b(a1.y); pk[6] = (short)f2b(a1.z); pk[7] = (short)f2b(a1.w);
            bh[ut][kt] = pk;
        }
    }
    const unsigned short* qbase = Qx + (size_t)(f * 48 + x) * 512 * 128;
    unsigned short* phbase = PH + (size_t)(f * 48 + x) * 512 * 48;
    for (int mt = 0; mt < 8; ++mt) {
        int rg = w * 128 + mt * 16 + lr;
        const unsigned short* qrow = qbase + (size_t)rg * 128;
        bf16x8 a[4];
#pragma unroll
        for (int kt = 0; kt < 4; ++kt) a[kt] = *(const bf16x8*)(qrow + kt * 32 + lk8);
        f32x4 acc[3] = {};
#pragma unroll
        for (int kt = 0; kt < 4; ++kt)
#pragma unroll
            for (int ut = 0; ut < 3; ++ut)
                acc[ut] = __builtin_amdgcn_mfma_f32_16x16x32_bf16(a[kt], bh[ut][kt], acc[ut], 0, 0, 0);
        __syncthreads();
#pragma unroll
        for (int ut = 0; ut < 3; ++ut)
#pragma unroll
            for (int r = 0; r < 4; ++r)
                sm[w][(l >> 4) * 4 + r][ut * 16 + lr] = acc[ut][r];
        __syncthreads();
        int part = l >> 4;
        float vb[12];
        float mx = -1e30f;
#pragma unroll
        for (int j = 0; j < 12; ++j) { vb[j] = sm[w][lr][part * 12 + j]; mx = fmaxf(mx, vb[j]); }
        mx = fmaxf(mx, __shfl_xor(mx, 16, 64));
        mx = fmaxf(mx, __shfl_xor(mx, 32, 64));
        float ssum = 0.f;
#pragma unroll
        for (int j = 0; j < 12; ++j) { vb[j] = __expf(vb[j] - mx); ssum += vb[j]; }
        ssum += __shfl_xor(ssum, 16, 64);
        ssum += __shfl_xor(ssum, 32, 64);
        float inv = 1.0f / ssum;
        unsigned short* dst = phbase + (size_t)(w * 128 + mt * 16 + lr) * 48 + part * 12;
#pragma unroll
        for (int j = 0; j < 12; ++j) dst[j] = f2b(vb[j] * inv);
    }
}

// ---------------- K2b: pw softmax over v ----------------
__global__ __launch_bounds__(256) void k_pw(const unsigned short* __restrict__ Qx,
                                            const float* __restrict__ rel_w,
                                            unsigned short* __restrict__ PW) {
    __shared__ float sm[4][16][68];
    int y = blockIdx.x, f = blockIdx.y;
    int tid = threadIdx.x, l = tid & 63, w = tid >> 6;
    int lr = l & 15, lk8 = (l >> 4) * 8;
    bf16x8 bw[4][4];
#pragma unroll
    for (int vt = 0; vt < 4; ++vt) {
        int v = vt * 16 + lr, rr = y - v + 99;
#pragma unroll
        for (int kt = 0; kt < 4; ++kt) {
            const float* s = rel_w + rr * 128 + kt * 32 + lk8;
            float4 a0 = *(const float4*)s, a1 = *(const float4*)(s + 4);
            bf16x8 pk;
            pk[0] = (short)f2b(a0.x); pk[1] = (short)f2b(a0.y); pk[2] = (short)f2b(a0.z); pk[3] = (short)f2b(a0.w);
            pk[4] = (short)f2b(a1.x); pk[5] = (short)f2b(a1.y); pk[6] = (short)f2b(a1.z); pk[7] = (short)f2b(a1.w);
            bw[vt][kt] = pk;
        }
    }
    for (int mt = 0; mt < 6; ++mt) {
        int rg = w * 96 + mt * 16 + lr;
        int bn = rg / 48, xx = rg - bn * 48;
        const unsigned short* qrow = Qx + (size_t)((f * 48 + xx) * 512 + bn * 64 + y) * 128;
        bf16x8 a[4];
#pragma unroll
        for (int kt = 0; kt < 4; ++kt) a[kt] = *(const bf16x8*)(qrow + kt * 32 + lk8);
        f32x4 acc[4] = {};
#pragma unroll
        for (int kt = 0; kt < 4; ++kt)
#pragma unroll
            for (int vt = 0; vt < 4; ++vt)
                acc[vt] = __builtin_amdgcn_mfma_f32_16x16x32_bf16(a[kt], bw[vt][kt], acc[vt], 0, 0, 0);
        __syncthreads();
#pragma unroll
        for (int vt = 0; vt < 4; ++vt)
#pragma unroll
            for (int r = 0; r < 4; ++r)
                sm[w][(l >> 4) * 4 + r][vt * 16 + lr] = acc[vt][r];
        __syncthreads();
        int part = l >> 4;
        float vb[16];
        float mx = -1e30f;
#pragma unroll
        for (int j = 0; j < 16; ++j) { vb[j] = sm[w][lr][part * 16 + j]; mx = fmaxf(mx, vb[j]); }
        mx = fmaxf(mx, __shfl_xor(mx, 16, 64));
        mx = fmaxf(mx, __shfl_xor(mx, 32, 64));
        float ssum = 0.f;
#pragma unroll
        for (int j = 0; j < 16; ++j) { vb[j] = __expf(vb[j] - mx); ssum += vb[j]; }
        ssum += __shfl_xor(ssum, 16, 64);
        ssum += __shfl_xor(ssum, 32, 64);
        float inv = 1.0f / ssum;
        unsigned short* dst = PW + (size_t)((f * 64 + y) * 384 + rg) * 64 + part * 16;
#pragma unroll
        for (int j = 0; j < 16; ++j) dst[j] = f2b(vb[j] * inv);
    }
}

// ---------------- K3 (Y-scheme): out[q,d] = sum_u ph[q,u] * (sum_v pw[q,v] V[u*64+v, d]) ----------------
// A-operand (pw rows) cached in VGPRs; per-u scale-accumulate; zero C-in via shared zero4.
__global__ __launch_bounds__(256) void k_attn(const unsigned short* __restrict__ PH,
                                              const unsigned short* __restrict__ PW,
                                              const unsigned short* __restrict__ Vt,
                                              unsigned short* __restrict__ AO) {
    __shared__ float phl[48 * 132];            // [u][q] f32, 25,344 B
    __shared__ unsigned short vtl[2][128 * 34]; // 17,408 B   (pad 34 -> stride 17 dwords, conflict-free)
    int bid = blockIdx.x;
    int r16 = bid & 15;
    int t = bid >> 4;                           // 0..23
    int fbn = (r16 & 7) * 2 + (r16 >> 3);       // XCD-local V reuse: xcd k hosts fbn {2k,2k+1}
    int f = fbn >> 3, bidx = (fbn >> 2) & 1, nh = fbn & 3;
    int fb = f * 2 + bidx, bn = bidx * 4 + nh;
    int tid = threadIdx.x;
    int l = tid & 63, w = tid >> 6;
    int wm = w >> 1, wn = w & 1;
    int lr = l & 15, lg = l >> 4, lk8 = lg * 8;

    // stage ph transposed [u][q] as f32
    for (int idx = tid; idx < 3072; idx += 256) {
        int q = idx & 127, up = idx >> 7;
        int xy = t * 128 + q, x = xy >> 6, y = xy & 63;
        unsigned int wv = *(const unsigned int*)(PH + ((size_t)(f * 48 + x) * 512 + bn * 64 + y) * 48 + up * 2);
        phl[(up * 2) * 132 + q] = b2f((unsigned short)(wv & 0xffffu));
        phl[(up * 2 + 1) * 132 + q] = b2f((unsigned short)(wv >> 16));
    }
    // A-cache: pw rows for this lane's 4 m-fragments, both k-halves
    bf16x8 a[4][2];
#pragma unroll
    for (int m = 0; m < 4; ++m) {
        int q = wm * 64 + m * 16 + lr;
        int xy = t * 128 + q, x = xy >> 6, y = xy & 63;
        const unsigned short* pwr = PW + ((size_t)(f * 64 + y) * 384 + bn * 48 + x) * 64;
        a[m][0] = *(const bf16x8*)(pwr + lk8);
        a[m][1] = *(const bf16x8*)(pwr + 32 + lk8);
    }
    const unsigned short* vsrc = Vt + (size_t)(fb * 4 + nh) * 128 * HWSZ;
    int d0 = tid >> 2, o0 = (tid & 3) * 8;
    int d1 = d0 + 64;
    {
        bf16x8 s0 = *(const bf16x8*)(vsrc + (size_t)d0 * HWSZ + o0);
        bf16x8 s1 = *(const bf16x8*)(vsrc + (size_t)d1 * HWSZ + o0);
        *(bf16x8*)&vtl[0][d0 * 34 + o0] = s0;
        *(bf16x8*)&vtl[0][d1 * 34 + o0] = s1;
    }
    __syncthreads();

    f32x4 out_acc[4][4] = {};
    const f32x4 zero4 = {0.f, 0.f, 0.f, 0.f};
    for (int u = 0; u < 48; ++u) {
        f32x4 phv[4];
#pragma unroll
        for (int m = 0; m < 4; ++m)
            phv[m] = *(const f32x4*)&phl[u * 132 + wm * 64 + m * 16 + lg * 4];
        f32x4 Y[4][4];
#pragma unroll
        for (int ks = 0; ks < 2; ++ks) {
            int kt = u * 2 + ks, cur = kt & 1;
            bf16x8 s0, s1;
            if (kt < 95) {
                const unsigned short* p = vsrc + (size_t)(kt + 1) * 32;
                s0 = *(const bf16x8*)(p + (size_t)d0 * HWSZ + o0);
                s1 = *(const bf16x8*)(p + (size_t)d1 * HWSZ + o0);
            }
            bf16x8 bv[4];
#pragma unroll
            for (int n = 0; n < 4; ++n)
                bv[n] = *(const bf16x8*)&vtl[cur][(wn * 64 + n * 16 + lr) * 34 + lk8];
#pragma unroll
            for (int m = 0; m < 4; ++m)
#pragma unroll
                for (int n = 0; n < 4; ++n)
                    Y[m][n] = __builtin_amdgcn_mfma_f32_16x16x32_bf16(a[m][ks], bv[n],
                                                                      ks ? Y[m][n] : zero4, 0, 0, 0);
            if (kt < 95) {
                *(bf16x8*)&vtl[cur ^ 1][d0 * 34 + o0] = s0;
                *(bf16x8*)&vtl[cur ^ 1][d1 * 34 + o0] = s1;
                __syncthreads();
            }
        }
#pragma unroll
        for (int m = 0; m < 4; ++m)
#pragma unroll
            for (int n = 0; n < 4; ++n)
                out_acc[m][n] += phv[m] * Y[m][n];
    }
    unsigned short* aobase = AO + (size_t)fb * HWSZ * 512 + nh * 128;
#pragma unroll
    for (int m = 0; m < 4; ++m)
#pragma unroll
        for (int n = 0; n < 4; ++n) {
            int dcol = wn * 64 + n * 16 + lr;
            int r0 = wm * 64 + m * 16 + lg * 4;
#pragma unroll
            for (int r = 0; r < 4; ++r) {
                int xy = t * 128 + r0 + r;
                aobase[(size_t)xy * 512 + dcol] = f2b(out_acc[m][n][r]);
            }
        }
}

// ---------------- K4: out = fmap + gamma * (AO @ Wp^T) ----------------
__global__ __launch_bounds__(256) void k_proj(const unsigned short* __restrict__ AO,
                                              const unsigned short* __restrict__ Wpb,
                                              const float* __restrict__ f0,
                                              const float* __restrict__ f1,
                                              const float* __restrict__ gamma,
                                              float* __restrict__ out) {
    __shared__ unsigned short Asub[64 * 136];
    __shared__ unsigned short Bsub[128 * 136];
    int t = blockIdx.x, fb = blockIdx.y;
    int f = fb >> 1, bb = fb & 1;
    int tid = threadIdx.x;
    int l = tid & 63, w = tid >> 6;
    int wm = w >> 1, wn = w & 1;
    int lr = l & 15, lk8 = (l >> 4) * 8;
    f32x4 acc[2][4] = {};
    for (int ks = 0; ks < 4; ++ks) {
        if (ks) __syncthreads();
        for (int ch = tid; ch < 1024; ch += 256) {
            int row = ch >> 4, seg = ch & 15;
            *(bf16x8*)&Asub[row * 136 + seg * 8] =
                *(const bf16x8*)(AO + (size_t)(fb * HWSZ + t * 64 + row) * 512 + ks * 128 + seg * 8);
        }
        for (int ch = tid; ch < 2048; ch += 256) {
            int row = ch >> 4, seg = ch & 15;
            *(bf16x8*)&Bsub[row * 136 + seg * 8] =
                *(const bf16x8*)(Wpb + (size_t)row * 512 + ks * 128 + seg * 8);
        }
        __syncthreads();
#pragma unroll
        for (int kt = 0; kt < 4; ++kt) {
            bf16x8 a[2], b[4];
#pragma unroll
            for (int m = 0; m < 2; ++m)
                a[m] = *(const bf16x8*)&Asub[(wm * 32 + m * 16 + lr) * 136 + kt * 32 + lk8];
#pragma unroll
            for (int n = 0; n < 4; ++n)
                b[n] = *(const bf16x8*)&Bsub[(wn * 64 + n * 16 + lr) * 136 + kt * 32 + lk8];
#pragma unroll
            for (int m = 0; m < 2; ++m)
#pragma unroll
                for (int n = 0; n < 4; ++n)
                    acc[m][n] = __builtin_amdgcn_mfma_f32_16x16x32_bf16(a[m], b[n], acc[m][n], 0, 0, 0);
        }
    }
    const float* fmapf = f ? f1 : f0;
    float g = gamma[0];
#pragma unroll
    for (int m = 0; m < 2; ++m)
#pragma unroll
        for (int n = 0; n < 4; ++n) {
            int c = wn * 64 + n * 16 + lr;
            int pos0 = t * 64 + wm * 32 + m * 16 + (l >> 4) * 4;
            size_t addr = (size_t)(bb * 128 + c) * HWSZ + pos0;
            float4 fv = *(const float4*)(fmapf + addr);
            float4 ov;
            ov.x = fv.x + g * acc[m][n][0];
            ov.y = fv.y + g * acc[m][n][1];
            ov.z = fv.z + g * acc[m][n][2];
            ov.w = fv.w + g * acc[m][n][3];
            *(float4*)(out + (size_t)f * 786432 + addr) = ov;
        }
}

extern "C" void kernel_launch(void* const* d_in, const int* in_sizes, int n_in,
                              void* d_out, int out_size, void* d_ws, size_t ws_size,
                              hipStream_t stream) {
    (void)in_sizes; (void)n_in; (void)out_size; (void)ws_size;
    const float* fmap1 = (const float*)d_in[0];
    const float* fmap2 = (const float*)d_in[1];
    const float* Wqk   = (const float*)d_in[2];
    const float* Wv    = (const float*)d_in[3];
    const float* rel_h = (const float*)d_in[4];
    const float* rel_w = (const float*)d_in[5];
    const float* Wp    = (const float*)d_in[6];
    const float* gamma = (const float*)d_in[7];
    float* out = (float*)d_out;
    char* ws = (char*)d_ws;

    unsigned short* Xb   = (unsigned short*)(ws + 0);
    unsigned short* Wcat = (unsigned short*)(ws + 3145728);
    unsigned short* Wpb  = (unsigned short*)(ws + 3407872);
    unsigned short* Qx   = (unsigned short*)(ws + 3538944);
    unsigned short* AO   = Qx;                               // alias: Qx dead after K2
    unsigned short* Vt   = (unsigned short*)(ws + 16121856);
    unsigned short* PH   = (unsigned short*)(ws + 28704768);
    unsigned short* PW   = (unsigned short*)(ws + 33423360);

    k_transpose<<<dim3(96, 4, 4), dim3(32, 8), 0, stream>>>(fmap1, fmap2, Xb);
    k_weights<<<dim3(768), dim3(256), 0, stream>>>(Wqk, Wv, Wp, Wcat, Wpb);
    k_qv<<<dim3(48, 8, 4), dim3(256), 0, stream>>>(Xb, Wcat, Qx, Vt);
    k_ph<<<dim3(48, 2), dim3(256), 0, stream>>>(Qx, rel_h, PH);
    k_pw<<<dim3(64, 2), dim3(256), 0, stream>>>(Qx, rel_w, PW);
    k_attn<<<dim3(384), dim3(256), 0, stream>>>(PH, PW, Vt, AO);
    k_proj<<<dim3(48, 4), dim3(256), 0, stream>>>(AO, Wpb, fmap1, fmap2, gamma, out);
}

// Round 4
// 168.533 us; speedup vs baseline: 1.0607x; 1.0167x over previous
//
#include <hip/hip_runtime.h>
#include <cstdint>
#include <cstddef>

typedef short bf16x8 __attribute__((ext_vector_type(8)));
typedef float f32x4 __attribute__((ext_vector_type(4)));

#define HH 48
#define WW 64
#define HWSZ 3072
#define SCALE_Q 0.08838834764831845f

__device__ __forceinline__ float b2f(unsigned short u) {
    union { unsigned int i; float f; } c; c.i = ((unsigned int)u) << 16; return c.f;
}
__device__ __forceinline__ unsigned short f2b(float f) {
    union { float f; unsigned int i; } c; c.f = f;
    unsigned int r = (c.i + 0x7fffu + ((c.i >> 16) & 1u)) >> 16;
    return (unsigned short)r;
}

// ---------------- K0a: fmap (fb, c, pos) f32 -> Xb (fb, pos, c) bf16 ----------------
__global__ __launch_bounds__(256) void k_transpose(const float* __restrict__ f0,
                                                   const float* __restrict__ f1,
                                                   unsigned short* __restrict__ Xb) {
    __shared__ float t[32][33];
    int fb = blockIdx.z; int f = fb >> 1, bb = fb & 1;
    const float* src = f ? f1 : f0;
    int pT = blockIdx.x * 32, cT = blockIdx.y * 32;
    int tx = threadIdx.x, ty = threadIdx.y;
#pragma unroll
    for (int i = 0; i < 4; ++i) {
        int c = cT + ty + i * 8, pos = pT + tx;
        t[ty + i * 8][tx] = src[(size_t)(bb * 128 + c) * HWSZ + pos];
    }
    __syncthreads();
#pragma unroll
    for (int i = 0; i < 4; ++i) {
        int pos = pT + ty + i * 8, c = cT + tx;
        Xb[(size_t)(fb * HWSZ + pos) * 128 + c] = f2b(t[tx][ty + i * 8]);
    }
}

// ---------------- K0b: weights -> bf16 ----------------
__global__ __launch_bounds__(256) void k_weights(const float* __restrict__ Wqk,
                                                 const float* __restrict__ Wv,
                                                 const float* __restrict__ Wp,
                                                 unsigned short* __restrict__ Wcat,
                                                 unsigned short* __restrict__ Wpb) {
    int idx = blockIdx.x * 256 + threadIdx.x;
    if (idx < 131072) {
        int o = idx >> 7, c = idx & 127;
        float v = (o < 512) ? Wqk[o * 128 + c] * SCALE_Q : Wv[(o - 512) * 128 + c];
        Wcat[idx] = f2b(v);
    } else {
        int j = idx - 131072;
        Wpb[j] = f2b(Wp[j]);
    }
}

// ---------------- K1: q/v projections ----------------
__global__ __launch_bounds__(256) void k_qv(const unsigned short* __restrict__ Xb,
                                            const unsigned short* __restrict__ Wcat,
                                            unsigned short* __restrict__ Qx,
                                            unsigned short* __restrict__ Vt) {
    __shared__ unsigned short Asub[64 * 136];
    __shared__ unsigned short Bsub[128 * 136];
    int mt = blockIdx.x, nt = blockIdx.y, fb = blockIdx.z;
    int tid = threadIdx.x;
    const unsigned short* asrc = Xb + (size_t)(fb * HWSZ + mt * 64) * 128;
    const unsigned short* bsrc = Wcat + (size_t)nt * 128 * 128;
    for (int ch = tid; ch < 1024; ch += 256) {
        int row = ch >> 4, seg = ch & 15;
        *(bf16x8*)&Asub[row * 136 + seg * 8] = *(const bf16x8*)(asrc + ch * 8);
    }
    for (int ch = tid; ch < 2048; ch += 256) {
        int row = ch >> 4, seg = ch & 15;
        *(bf16x8*)&Bsub[row * 136 + seg * 8] = *(const bf16x8*)(bsrc + ch * 8);
    }
    __syncthreads();
    int l = tid & 63, w = tid >> 6;
    int wm = w >> 1, wn = w & 1;
    int lr = l & 15, lk8 = (l >> 4) * 8;
    f32x4 acc[2][4] = {};
#pragma unroll
    for (int kt = 0; kt < 4; ++kt) {
        bf16x8 a[2], b[4];
#pragma unroll
        for (int m = 0; m < 2; ++m)
            a[m] = *(const bf16x8*)&Asub[(wm * 32 + m * 16 + lr) * 136 + kt * 32 + lk8];
#pragma unroll
        for (int n = 0; n < 4; ++n)
            b[n] = *(const bf16x8*)&Bsub[(wn * 64 + n * 16 + lr) * 136 + kt * 32 + lk8];
#pragma unroll
        for (int m = 0; m < 2; ++m)
#pragma unroll
            for (int n = 0; n < 4; ++n)
                acc[m][n] = __builtin_amdgcn_mfma_f32_16x16x32_bf16(a[m], b[n], acc[m][n], 0, 0, 0);
    }
    int f = fb >> 1, bb = fb & 1;
#pragma unroll
    for (int m = 0; m < 2; ++m)
#pragma unroll
        for (int n = 0; n < 4; ++n) {
            int o = nt * 128 + wn * 64 + n * 16 + lr;
            int pos0 = mt * 64 + wm * 32 + m * 16 + (l >> 4) * 4;
            if (o < 512) {
                int nh = o >> 7, d = o & 127;
#pragma unroll
                for (int r = 0; r < 4; ++r) {
                    int pos = pos0 + r, x = pos >> 6, y = pos & 63;
                    Qx[(size_t)((f * 48 + x) * 512 + (bb * 4 + nh) * 64 + y) * 128 + d] = f2b(acc[m][n][r]);
                }
            } else {
                int oo = o - 512, nh = oo >> 7, d = oo & 127;
                uint2 val;
                val.x = (unsigned int)f2b(acc[m][n][0]) | ((unsigned int)f2b(acc[m][n][1]) << 16);
                val.y = (unsigned int)f2b(acc[m][n][2]) | ((unsigned int)f2b(acc[m][n][3]) << 16);
                *(uint2*)&Vt[(size_t)((fb * 4 + nh) * 128 + d) * HWSZ + pos0] = val;
            }
        }
}

// ---------------- K2a: ph softmax over u ----------------
__global__ __launch_bounds__(256) void k_ph(const unsigned short* __restrict__ Qx,
                                            const float* __restrict__ rel_h,
                                            unsigned short* __restrict__ PH) {
    __shared__ float sm[4][16][52];
    int x = blockIdx.x, f = blockIdx.y;
    int tid = threadIdx.x, l = tid & 63, w = tid >> 6;
    int lr = l & 15, lk8 = (l >> 4) * 8;
    bf16x8 bh[3][4];
#pragma unroll
    for (int ut = 0; ut < 3; ++ut) {
        int u = ut * 16 + lr, rr = x - u + 99;
#pragma unroll
        for (int kt = 0; kt < 4; ++kt) {
            const float* s = rel_h + rr * 128 + kt * 32 + lk8;
            float4 a0 = *(const float4*)s, a1 = *(const float4*)(s + 4);
            bf16x8 pk;
            pk[0] = (short)f2b(a0.x); pk[1] = (short)f2b(a0.y); pk[2] = (short)f2b(a0.z); pk[3] = (short)f2b(a0.w);
            pk[4] = (short)f2b(a1.x); pk[5] = (short)f2b(a1.y); pk[6] = (short)f2b(a1.z); pk[7] = (short)f2b(a1.w);
            bh[ut][kt] = pk;
        }
    }
    const unsigned short* qbase = Qx + (size_t)(f * 48 + x) * 512 * 128;
    unsigned short* phbase = PH + (size_t)(f * 48 + x) * 512 * 48;
    for (int mt = 0; mt < 8; ++mt) {
        int rg = w * 128 + mt * 16 + lr;
        const unsigned short* qrow = qbase + (size_t)rg * 128;
        bf16x8 a[4];
#pragma unroll
        for (int kt = 0; kt < 4; ++kt) a[kt] = *(const bf16x8*)(qrow + kt * 32 + lk8);
        f32x4 acc[3] = {};
#pragma unroll
        for (int kt = 0; kt < 4; ++kt)
#pragma unroll
            for (int ut = 0; ut < 3; ++ut)
                acc[ut] = __builtin_amdgcn_mfma_f32_16x16x32_bf16(a[kt], bh[ut][kt], acc[ut], 0, 0, 0);
        __syncthreads();
#pragma unroll
        for (int ut = 0; ut < 3; ++ut)
#pragma unroll
            for (int r = 0; r < 4; ++r)
                sm[w][(l >> 4) * 4 + r][ut * 16 + lr] = acc[ut][r];
        __syncthreads();
        int part = l >> 4;
        float vb[12];
        float mx = -1e30f;
#pragma unroll
        for (int j = 0; j < 12; ++j) { vb[j] = sm[w][lr][part * 12 + j]; mx = fmaxf(mx, vb[j]); }
        mx = fmaxf(mx, __shfl_xor(mx, 16, 64));
        mx = fmaxf(mx, __shfl_xor(mx, 32, 64));
        float ssum = 0.f;
#pragma unroll
        for (int j = 0; j < 12; ++j) { vb[j] = __expf(vb[j] - mx); ssum += vb[j]; }
        ssum += __shfl_xor(ssum, 16, 64);
        ssum += __shfl_xor(ssum, 32, 64);
        float inv = 1.0f / ssum;
        unsigned short* dst = phbase + (size_t)(w * 128 + mt * 16 + lr) * 48 + part * 12;
#pragma unroll
        for (int j = 0; j < 12; ++j) dst[j] = f2b(vb[j] * inv);
    }
}

// ---------------- K2b: pw softmax over v ----------------
__global__ __launch_bounds__(256) void k_pw(const unsigned short* __restrict__ Qx,
                                            const float* __restrict__ rel_w,
                                            unsigned short* __restrict__ PW) {
    __shared__ float sm[4][16][68];
    int y = blockIdx.x, f = blockIdx.y;
    int tid = threadIdx.x, l = tid & 63, w = tid >> 6;
    int lr = l & 15, lk8 = (l >> 4) * 8;
    bf16x8 bw[4][4];
#pragma unroll
    for (int vt = 0; vt < 4; ++vt) {
        int v = vt * 16 + lr, rr = y - v + 99;
#pragma unroll
        for (int kt = 0; kt < 4; ++kt) {
            const float* s = rel_w + rr * 128 + kt * 32 + lk8;
            float4 a0 = *(const float4*)s, a1 = *(const float4*)(s + 4);
            bf16x8 pk;
            pk[0] = (short)f2b(a0.x); pk[1] = (short)f2b(a0.y); pk[2] = (short)f2b(a0.z); pk[3] = (short)f2b(a0.w);
            pk[4] = (short)f2b(a1.x); pk[5] = (short)f2b(a1.y); pk[6] = (short)f2b(a1.z); pk[7] = (short)f2b(a1.w);
            bw[vt][kt] = pk;
        }
    }
    for (int mt = 0; mt < 6; ++mt) {
        int rg = w * 96 + mt * 16 + lr;
        int bn = rg / 48, xx = rg - bn * 48;
        const unsigned short* qrow = Qx + (size_t)((f * 48 + xx) * 512 + bn * 64 + y) * 128;
        bf16x8 a[4];
#pragma unroll
        for (int kt = 0; kt < 4; ++kt) a[kt] = *(const bf16x8*)(qrow + kt * 32 + lk8);
        f32x4 acc[4] = {};
#pragma unroll
        for (int kt = 0; kt < 4; ++kt)
#pragma unroll
            for (int vt = 0; vt < 4; ++vt)
                acc[vt] = __builtin_amdgcn_mfma_f32_16x16x32_bf16(a[kt], bw[vt][kt], acc[vt], 0, 0, 0);
        __syncthreads();
#pragma unroll
        for (int vt = 0; vt < 4; ++vt)
#pragma unroll
            for (int r = 0; r < 4; ++r)
                sm[w][(l >> 4) * 4 + r][vt * 16 + lr] = acc[vt][r];
        __syncthreads();
        int part = l >> 4;
        float vb[16];
        float mx = -1e30f;
#pragma unroll
        for (int j = 0; j < 16; ++j) { vb[j] = sm[w][lr][part * 16 + j]; mx = fmaxf(mx, vb[j]); }
        mx = fmaxf(mx, __shfl_xor(mx, 16, 64));
        mx = fmaxf(mx, __shfl_xor(mx, 32, 64));
        float ssum = 0.f;
#pragma unroll
        for (int j = 0; j < 16; ++j) { vb[j] = __expf(vb[j] - mx); ssum += vb[j]; }
        ssum += __shfl_xor(ssum, 16, 64);
        ssum += __shfl_xor(ssum, 32, 64);
        float inv = 1.0f / ssum;
        unsigned short* dst = PW + (size_t)((f * 64 + y) * 384 + rg) * 64 + part * 16;
#pragma unroll
        for (int j = 0; j < 16; ++j) dst[j] = f2b(vb[j] * inv);
    }
}

// ---------------- K3 (barrier-free): out[q,d] = sum_u ph[q,u] * (sum_v pw[q,v] V[u*64+v, d]) ----------------
// B-fragments loaded global->reg (V is L2/L1 resident), depth-2 register pipeline, no LDS V tile,
// no barriers in the main loop.
__global__ __launch_bounds__(256) void k_attn(const unsigned short* __restrict__ PH,
                                              const unsigned short* __restrict__ PW,
                                              const unsigned short* __restrict__ Vt,
                                              unsigned short* __restrict__ AO) {
    __shared__ float phl[48 * 132];            // [u][q] f32, broadcast reads
    int bid = blockIdx.x;
    int r16 = bid & 15;
    int t = bid >> 4;                           // 0..23
    int fbn = (r16 & 7) * 2 + (r16 >> 3);       // XCD-local V reuse
    int f = fbn >> 3, bidx = (fbn >> 2) & 1, nh = fbn & 3;
    int fb = f * 2 + bidx, bn = bidx * 4 + nh;
    int tid = threadIdx.x;
    int l = tid & 63, w = tid >> 6;
    int wm = w >> 1, wn = w & 1;
    int lr = l & 15, lg = l >> 4, lk8 = lg * 8;

    // stage ph transposed [u][q] as f32
    for (int idx = tid; idx < 3072; idx += 256) {
        int q = idx & 127, up = idx >> 7;
        int xy = t * 128 + q, x = xy >> 6, y = xy & 63;
        unsigned int wv = *(const unsigned int*)(PH + ((size_t)(f * 48 + x) * 512 + bn * 64 + y) * 48 + up * 2);
        phl[(up * 2) * 132 + q] = b2f((unsigned short)(wv & 0xffffu));
        phl[(up * 2 + 1) * 132 + q] = b2f((unsigned short)(wv >> 16));
    }
    // A-cache: pw rows for this lane's 4 m-fragments, both k-halves
    bf16x8 a[4][2];
#pragma unroll
    for (int m = 0; m < 4; ++m) {
        int q = wm * 64 + m * 16 + lr;
        int xy = t * 128 + q, x = xy >> 6, y = xy & 63;
        const unsigned short* pwr = PW + ((size_t)(f * 64 + y) * 384 + bn * 48 + x) * 64;
        a[m][0] = *(const bf16x8*)(pwr + lk8);
        a[m][1] = *(const bf16x8*)(pwr + 32 + lk8);
    }
    __syncthreads();

    // per-lane V base for B-fragments: row = wn*64 + n*16 + lr, col chunk = kt*32 + lk8
    const unsigned short* vsrc = Vt + (size_t)(fb * 4 + nh) * 128 * HWSZ;
    const unsigned short* vrow[4];
#pragma unroll
    for (int n = 0; n < 4; ++n)
        vrow[n] = vsrc + (size_t)(wn * 64 + n * 16 + lr) * HWSZ + lk8;

    // prologue: preload kt=0 -> setA, kt=1 -> setB
    bf16x8 bvA[4], bvB[4];
#pragma unroll
    for (int n = 0; n < 4; ++n) bvA[n] = *(const bf16x8*)(vrow[n] + 0 * 32);
#pragma unroll
    for (int n = 0; n < 4; ++n) bvB[n] = *(const bf16x8*)(vrow[n] + 1 * 32);

    f32x4 out_acc[4][4] = {};
    const f32x4 zero4 = {0.f, 0.f, 0.f, 0.f};
    for (int u = 0; u < 48; ++u) {
        f32x4 phv[4];
#pragma unroll
        for (int m = 0; m < 4; ++m)
            phv[m] = *(const f32x4*)&phl[u * 132 + wm * 64 + m * 16 + lg * 4];
        f32x4 Y[4][4];
        // ks = 0: consume setA (kt = 2u), then refill setA with kt = 2u+2
        {
#pragma unroll
            for (int m = 0; m < 4; ++m)
#pragma unroll
                for (int n = 0; n < 4; ++n)
                    Y[m][n] = __builtin_amdgcn_mfma_f32_16x16x32_bf16(a[m][0], bvA[n], zero4, 0, 0, 0);
            int ktn = 2 * u + 2; if (ktn > 95) ktn = 95;
#pragma unroll
            for (int n = 0; n < 4; ++n) bvA[n] = *(const bf16x8*)(vrow[n] + (size_t)ktn * 32);
        }
        // ks = 1: consume setB (kt = 2u+1), then refill setB with kt = 2u+3
        {
#pragma unroll
            for (int m = 0; m < 4; ++m)
#pragma unroll
                for (int n = 0; n < 4; ++n)
                    Y[m][n] = __builtin_amdgcn_mfma_f32_16x16x32_bf16(a[m][1], bvB[n], Y[m][n], 0, 0, 0);
            int ktn = 2 * u + 3; if (ktn > 95) ktn = 95;
#pragma unroll
            for (int n = 0; n < 4; ++n) bvB[n] = *(const bf16x8*)(vrow[n] + (size_t)ktn * 32);
        }
#pragma unroll
        for (int m = 0; m < 4; ++m)
#pragma unroll
            for (int n = 0; n < 4; ++n)
                out_acc[m][n] += phv[m] * Y[m][n];
    }
    unsigned short* aobase = AO + (size_t)fb * HWSZ * 512 + nh * 128;
#pragma unroll
    for (int m = 0; m < 4; ++m)
#pragma unroll
        for (int n = 0; n < 4; ++n) {
            int dcol = wn * 64 + n * 16 + lr;
            int r0 = wm * 64 + m * 16 + lg * 4;
#pragma unroll
            for (int r = 0; r < 4; ++r) {
                int xy = t * 128 + r0 + r;
                aobase[(size_t)xy * 512 + dcol] = f2b(out_acc[m][n][r]);
            }
        }
}

// ---------------- K4: out = fmap + gamma * (AO @ Wp^T) ----------------
__global__ __launch_bounds__(256) void k_proj(const unsigned short* __restrict__ AO,
                                              const unsigned short* __restrict__ Wpb,
                                              const float* __restrict__ f0,
                                              const float* __restrict__ f1,
                                              const float* __restrict__ gamma,
                                              float* __restrict__ out) {
    __shared__ unsigned short Asub[64 * 136];
    __shared__ unsigned short Bsub[128 * 136];
    int t = blockIdx.x, fb = blockIdx.y;
    int f = fb >> 1, bb = fb & 1;
    int tid = threadIdx.x;
    int l = tid & 63, w = tid >> 6;
    int wm = w >> 1, wn = w & 1;
    int lr = l & 15, lk8 = (l >> 4) * 8;
    f32x4 acc[2][4] = {};
    for (int ks = 0; ks < 4; ++ks) {
        if (ks) __syncthreads();
        for (int ch = tid; ch < 1024; ch += 256) {
            int row = ch >> 4, seg = ch & 15;
            *(bf16x8*)&Asub[row * 136 + seg * 8] =
                *(const bf16x8*)(AO + (size_t)(fb * HWSZ + t * 64 + row) * 512 + ks * 128 + seg * 8);
        }
        for (int ch = tid; ch < 2048; ch += 256) {
            int row = ch >> 4, seg = ch & 15;
            *(bf16x8*)&Bsub[row * 136 + seg * 8] =
                *(const bf16x8*)(Wpb + (size_t)row * 512 + ks * 128 + seg * 8);
        }
        __syncthreads();
#pragma unroll
        for (int kt = 0; kt < 4; ++kt) {
            bf16x8 a[2], b[4];
#pragma unroll
            for (int m = 0; m < 2; ++m)
                a[m] = *(const bf16x8*)&Asub[(wm * 32 + m * 16 + lr) * 136 + kt * 32 + lk8];
#pragma unroll
            for (int n = 0; n < 4; ++n)
                b[n] = *(const bf16x8*)&Bsub[(wn * 64 + n * 16 + lr) * 136 + kt * 32 + lk8];
#pragma unroll
            for (int m = 0; m < 2; ++m)
#pragma unroll
                for (int n = 0; n < 4; ++n)
                    acc[m][n] = __builtin_amdgcn_mfma_f32_16x16x32_bf16(a[m], b[n], acc[m][n], 0, 0, 0);
        }
    }
    const float* fmapf = f ? f1 : f0;
    float g = gamma[0];
#pragma unroll
    for (int m = 0; m < 2; ++m)
#pragma unroll
        for (int n = 0; n < 4; ++n) {
            int c = wn * 64 + n * 16 + lr;
            int pos0 = t * 64 + wm * 32 + m * 16 + (l >> 4) * 4;
            size_t addr = (size_t)(bb * 128 + c) * HWSZ + pos0;
            float4 fv = *(const float4*)(fmapf + addr);
            float4 ov;
            ov.x = fv.x + g * acc[m][n][0];
            ov.y = fv.y + g * acc[m][n][1];
            ov.z = fv.z + g * acc[m][n][2];
            ov.w = fv.w + g * acc[m][n][3];
            *(float4*)(out + (size_t)f * 786432 + addr) = ov;
        }
}

extern "C" void kernel_launch(void* const* d_in, const int* in_sizes, int n_in,
                              void* d_out, int out_size, void* d_ws, size_t ws_size,
                              hipStream_t stream) {
    (void)in_sizes; (void)n_in; (void)out_size; (void)ws_size;
    const float* fmap1 = (const float*)d_in[0];
    const float* fmap2 = (const float*)d_in[1];
    const float* Wqk   = (const float*)d_in[2];
    const float* Wv    = (const float*)d_in[3];
    const float* rel_h = (const float*)d_in[4];
    const float* rel_w = (const float*)d_in[5];
    const float* Wp    = (const float*)d_in[6];
    const float* gamma = (const float*)d_in[7];
    float* out = (float*)d_out;
    char* ws = (char*)d_ws;

    unsigned short* Xb   = (unsigned short*)(ws + 0);
    unsigned short* Wcat = (unsigned short*)(ws + 3145728);
    unsigned short* Wpb  = (unsigned short*)(ws + 3407872);
    unsigned short* Qx   = (unsigned short*)(ws + 3538944);
    unsigned short* AO   = Qx;                               // alias: Qx dead after K2
    unsigned short* Vt   = (unsigned short*)(ws + 16121856);
    unsigned short* PH   = (unsigned short*)(ws + 28704768);
    unsigned short* PW   = (unsigned short*)(ws + 33423360);

    k_transpose<<<dim3(96, 4, 4), dim3(32, 8), 0, stream>>>(fmap1, fmap2, Xb);
    k_weights<<<dim3(768), dim3(256), 0, stream>>>(Wqk, Wv, Wp, Wcat, Wpb);
    k_qv<<<dim3(48, 8, 4), dim3(256), 0, stream>>>(Xb, Wcat, Qx, Vt);
    k_ph<<<dim3(48, 2), dim3(256), 0, stream>>>(Qx, rel_h, PH);
    k_pw<<<dim3(64, 2), dim3(256), 0, stream>>>(Qx, rel_w, PW);
    k_attn<<<dim3(384), dim3(256), 0, stream>>>(PH, PW, Vt, AO);
    k_proj<<<dim3(48, 4), dim3(256), 0, stream>>>(AO, Wpb, fmap1, fmap2, gamma, out);
}

// Round 6
// 155.438 us; speedup vs baseline: 1.1500x; 1.0842x over previous
//
#include <hip/hip_runtime.h>
#include <cstdint>
#include <cstddef>

typedef short bf16x8 __attribute__((ext_vector_type(8)));
typedef float f32x4 __attribute__((ext_vector_type(4)));

#define HH 48
#define WW 64
#define HWSZ 3072
#define SCALE_Q 0.08838834764831845f

__device__ __forceinline__ float b2f(unsigned short u) {
    union { unsigned int i; float f; } c; c.i = ((unsigned int)u) << 16; return c.f;
}
__device__ __forceinline__ unsigned short f2b(float f) {
    union { float f; unsigned int i; } c; c.f = f;
    unsigned int r = (c.i + 0x7fffu + ((c.i >> 16) & 1u)) >> 16;
    return (unsigned short)r;
}

// ---------------- K0a: fmap (fb, c, pos) f32 -> Xb (fb, pos, c) bf16 ----------------
__global__ __launch_bounds__(256) void k_transpose(const float* __restrict__ f0,
                                                   const float* __restrict__ f1,
                                                   unsigned short* __restrict__ Xb) {
    __shared__ float t[32][33];
    int fb = blockIdx.z; int f = fb >> 1, bb = fb & 1;
    const float* src = f ? f1 : f0;
    int pT = blockIdx.x * 32, cT = blockIdx.y * 32;
    int tx = threadIdx.x, ty = threadIdx.y;
#pragma unroll
    for (int i = 0; i < 4; ++i) {
        int c = cT + ty + i * 8, pos = pT + tx;
        t[ty + i * 8][tx] = src[(size_t)(bb * 128 + c) * HWSZ + pos];
    }
    __syncthreads();
#pragma unroll
    for (int i = 0; i < 4; ++i) {
        int pos = pT + ty + i * 8, c = cT + tx;
        Xb[(size_t)(fb * HWSZ + pos) * 128 + c] = f2b(t[tx][ty + i * 8]);
    }
}

// ---------------- K0b: weights -> bf16 ----------------
__global__ __launch_bounds__(256) void k_weights(const float* __restrict__ Wqk,
                                                 const float* __restrict__ Wv,
                                                 const float* __restrict__ Wp,
                                                 unsigned short* __restrict__ Wcat,
                                                 unsigned short* __restrict__ Wpb) {
    int idx = blockIdx.x * 256 + threadIdx.x;
    if (idx < 131072) {
        int o = idx >> 7, c = idx & 127;
        float v = (o < 512) ? Wqk[o * 128 + c] * SCALE_Q : Wv[(o - 512) * 128 + c];
        Wcat[idx] = f2b(v);
    } else {
        int j = idx - 131072;
        Wpb[j] = f2b(Wp[j]);
    }
}

// ---------------- K1: q/v projections ----------------
__global__ __launch_bounds__(256) void k_qv(const unsigned short* __restrict__ Xb,
                                            const unsigned short* __restrict__ Wcat,
                                            unsigned short* __restrict__ Qx,
                                            unsigned short* __restrict__ Vt) {
    __shared__ unsigned short Asub[64 * 136];
    __shared__ unsigned short Bsub[128 * 136];
    int mt = blockIdx.x, nt = blockIdx.y, fb = blockIdx.z;
    int tid = threadIdx.x;
    const unsigned short* asrc = Xb + (size_t)(fb * HWSZ + mt * 64) * 128;
    const unsigned short* bsrc = Wcat + (size_t)nt * 128 * 128;
    for (int ch = tid; ch < 1024; ch += 256) {
        int row = ch >> 4, seg = ch & 15;
        *(bf16x8*)&Asub[row * 136 + seg * 8] = *(const bf16x8*)(asrc + ch * 8);
    }
    for (int ch = tid; ch < 2048; ch += 256) {
        int row = ch >> 4, seg = ch & 15;
        *(bf16x8*)&Bsub[row * 136 + seg * 8] = *(const bf16x8*)(bsrc + ch * 8);
    }
    __syncthreads();
    int l = tid & 63, w = tid >> 6;
    int wm = w >> 1, wn = w & 1;
    int lr = l & 15, lk8 = (l >> 4) * 8;
    f32x4 acc[2][4] = {};
#pragma unroll
    for (int kt = 0; kt < 4; ++kt) {
        bf16x8 a[2], b[4];
#pragma unroll
        for (int m = 0; m < 2; ++m)
            a[m] = *(const bf16x8*)&Asub[(wm * 32 + m * 16 + lr) * 136 + kt * 32 + lk8];
#pragma unroll
        for (int n = 0; n < 4; ++n)
            b[n] = *(const bf16x8*)&Bsub[(wn * 64 + n * 16 + lr) * 136 + kt * 32 + lk8];
#pragma unroll
        for (int m = 0; m < 2; ++m)
#pragma unroll
            for (int n = 0; n < 4; ++n)
                acc[m][n] = __builtin_amdgcn_mfma_f32_16x16x32_bf16(a[m], b[n], acc[m][n], 0, 0, 0);
    }
    int f = fb >> 1, bb = fb & 1;
#pragma unroll
    for (int m = 0; m < 2; ++m)
#pragma unroll
        for (int n = 0; n < 4; ++n) {
            int o = nt * 128 + wn * 64 + n * 16 + lr;
            int pos0 = mt * 64 + wm * 32 + m * 16 + (l >> 4) * 4;
            if (o < 512) {
                int nh = o >> 7, d = o & 127;
#pragma unroll
                for (int r = 0; r < 4; ++r) {
                    int pos = pos0 + r, x = pos >> 6, y = pos & 63;
                    Qx[(size_t)((f * 48 + x) * 512 + (bb * 4 + nh) * 64 + y) * 128 + d] = f2b(acc[m][n][r]);
                }
            } else {
                int oo = o - 512, nh = oo >> 7, d = oo & 127;
                uint2 val;
                val.x = (unsigned int)f2b(acc[m][n][0]) | ((unsigned int)f2b(acc[m][n][1]) << 16);
                val.y = (unsigned int)f2b(acc[m][n][2]) | ((unsigned int)f2b(acc[m][n][3]) << 16);
                *(uint2*)&Vt[(size_t)((fb * 4 + nh) * 128 + d) * HWSZ + pos0] = val;
            }
        }
}

// ---------------- K2a: ph softmax over u ----------------
__global__ __launch_bounds__(256) void k_ph(const unsigned short* __restrict__ Qx,
                                            const float* __restrict__ rel_h,
                                            unsigned short* __restrict__ PH) {
    __shared__ float sm[4][16][52];
    int x = blockIdx.x, f = blockIdx.y;
    int tid = threadIdx.x, l = tid & 63, w = tid >> 6;
    int lr = l & 15, lk8 = (l >> 4) * 8;
    bf16x8 bh[3][4];
#pragma unroll
    for (int ut = 0; ut < 3; ++ut) {
        int u = ut * 16 + lr, rr = x - u + 99;
#pragma unroll
        for (int kt = 0; kt < 4; ++kt) {
            const float* s = rel_h + rr * 128 + kt * 32 + lk8;
            float4 a0 = *(const float4*)s, a1 = *(const float4*)(s + 4);
            bf16x8 pk;
            pk[0] = (short)f2b(a0.x); pk[1] = (short)f2b(a0.y); pk[2] = (short)f2b(a0.z); pk[3] = (short)f2b(a0.w);
            pk[4] = (short)f2b(a1.x); pk[5] = (short)f2b(a1.y); pk[6] = (short)f2b(a1.z); pk[7] = (short)f2b(a1.w);
            bh[ut][kt] = pk;
        }
    }
    const unsigned short* qbase = Qx + (size_t)(f * 48 + x) * 512 * 128;
    unsigned short* phbase = PH + (size_t)(f * 48 + x) * 512 * 48;
    for (int mt = 0; mt < 8; ++mt) {
        int rg = w * 128 + mt * 16 + lr;
        const unsigned short* qrow = qbase + (size_t)rg * 128;
        bf16x8 a[4];
#pragma unroll
        for (int kt = 0; kt < 4; ++kt) a[kt] = *(const bf16x8*)(qrow + kt * 32 + lk8);
        f32x4 acc[3] = {};
#pragma unroll
        for (int kt = 0; kt < 4; ++kt)
#pragma unroll
            for (int ut = 0; ut < 3; ++ut)
                acc[ut] = __builtin_amdgcn_mfma_f32_16x16x32_bf16(a[kt], bh[ut][kt], acc[ut], 0, 0, 0);
        __syncthreads();
#pragma unroll
        for (int ut = 0; ut < 3; ++ut)
#pragma unroll
            for (int r = 0; r < 4; ++r)
                sm[w][(l >> 4) * 4 + r][ut * 16 + lr] = acc[ut][r];
        __syncthreads();
        int part = l >> 4;
        float vb[12];
        float mx = -1e30f;
#pragma unroll
        for (int j = 0; j < 12; ++j) { vb[j] = sm[w][lr][part * 12 + j]; mx = fmaxf(mx, vb[j]); }
        mx = fmaxf(mx, __shfl_xor(mx, 16, 64));
        mx = fmaxf(mx, __shfl_xor(mx, 32, 64));
        float ssum = 0.f;
#pragma unroll
        for (int j = 0; j < 12; ++j) { vb[j] = __expf(vb[j] - mx); ssum += vb[j]; }
        ssum += __shfl_xor(ssum, 16, 64);
        ssum += __shfl_xor(ssum, 32, 64);
        float inv = 1.0f / ssum;
        unsigned short* dst = phbase + (size_t)(w * 128 + mt * 16 + lr) * 48 + part * 12;
#pragma unroll
        for (int j = 0; j < 12; ++j) dst[j] = f2b(vb[j] * inv);
    }
}

// ---------------- K2b: pw softmax over v ----------------
__global__ __launch_bounds__(256) void k_pw(const unsigned short* __restrict__ Qx,
                                            const float* __restrict__ rel_w,
                                            unsigned short* __restrict__ PW) {
    __shared__ float sm[4][16][68];
    int y = blockIdx.x, f = blockIdx.y;
    int tid = threadIdx.x, l = tid & 63, w = tid >> 6;
    int lr = l & 15, lk8 = (l >> 4) * 8;
    bf16x8 bw[4][4];
#pragma unroll
    for (int vt = 0; vt < 4; ++vt) {
        int v = vt * 16 + lr, rr = y - v + 99;
#pragma unroll
        for (int kt = 0; kt < 4; ++kt) {
            const float* s = rel_w + rr * 128 + kt * 32 + lk8;
            float4 a0 = *(const float4*)s, a1 = *(const float4*)(s + 4);
            bf16x8 pk;
            pk[0] = (short)f2b(a0.x); pk[1] = (short)f2b(a0.y); pk[2] = (short)f2b(a0.z); pk[3] = (short)f2b(a0.w);
            pk[4] = (short)f2b(a1.x); pk[5] = (short)f2b(a1.y); pk[6] = (short)f2b(a1.z); pk[7] = (short)f2b(a1.w);
            bw[vt][kt] = pk;
        }
    }
    for (int mt = 0; mt < 6; ++mt) {
        int rg = w * 96 + mt * 16 + lr;
        int bn = rg / 48, xx = rg - bn * 48;
        const unsigned short* qrow = Qx + (size_t)((f * 48 + xx) * 512 + bn * 64 + y) * 128;
        bf16x8 a[4];
#pragma unroll
        for (int kt = 0; kt < 4; ++kt) a[kt] = *(const bf16x8*)(qrow + kt * 32 + lk8);
        f32x4 acc[4] = {};
#pragma unroll
        for (int kt = 0; kt < 4; ++kt)
#pragma unroll
            for (int vt = 0; vt < 4; ++vt)
                acc[vt] = __builtin_amdgcn_mfma_f32_16x16x32_bf16(a[kt], bw[vt][kt], acc[vt], 0, 0, 0);
        __syncthreads();
#pragma unroll
        for (int vt = 0; vt < 4; ++vt)
#pragma unroll
            for (int r = 0; r < 4; ++r)
                sm[w][(l >> 4) * 4 + r][vt * 16 + lr] = acc[vt][r];
        __syncthreads();
        int part = l >> 4;
        float vb[16];
        float mx = -1e30f;
#pragma unroll
        for (int j = 0; j < 16; ++j) { vb[j] = sm[w][lr][part * 16 + j]; mx = fmaxf(mx, vb[j]); }
        mx = fmaxf(mx, __shfl_xor(mx, 16, 64));
        mx = fmaxf(mx, __shfl_xor(mx, 32, 64));
        float ssum = 0.f;
#pragma unroll
        for (int j = 0; j < 16; ++j) { vb[j] = __expf(vb[j] - mx); ssum += vb[j]; }
        ssum += __shfl_xor(ssum, 16, 64);
        ssum += __shfl_xor(ssum, 32, 64);
        float inv = 1.0f / ssum;
        unsigned short* dst = PW + (size_t)((f * 64 + y) * 384 + rg) * 64 + part * 16;
#pragma unroll
        for (int j = 0; j < 16; ++j) dst[j] = f2b(vb[j] * inv);
    }
}

// ---------------- K3 (barrier-free, d-split): out[q,d] = sum_u ph[q,u] * (sum_v pw[q,v] V[u*64+v, d]) ----------------
// Grid 768 = 24 q-tiles x 2 d-halves x 16 (f,b,n): 3 blocks/CU for latency hiding.
// B-fragments global->reg (V is XCD-L2 resident), depth-2 register pipeline, no main-loop barriers.
__global__ __launch_bounds__(256) void k_attn(const unsigned short* __restrict__ PH,
                                              const unsigned short* __restrict__ PW,
                                              const unsigned short* __restrict__ Vt,
                                              unsigned short* __restrict__ AO) {
    __shared__ float phl[48 * 132];            // [u][q] f32, broadcast reads
    int bid = blockIdx.x;
    int r16 = bid & 15;
    int th = bid >> 4;                          // 0..47
    int t = th >> 1, dh = th & 1;               // q-tile, d-half
    int fbn = (r16 & 7) * 2 + (r16 >> 3);       // XCD-local V reuse
    int f = fbn >> 3, bidx = (fbn >> 2) & 1, nh = fbn & 3;
    int fb = f * 2 + bidx, bn = bidx * 4 + nh;
    int tid = threadIdx.x;
    int l = tid & 63, w = tid >> 6;
    int wm = w >> 1, wn = w & 1;
    int lr = l & 15, lg = l >> 4, lk8 = lg * 8;

    // stage ph transposed [u][q] as f32
    for (int idx = tid; idx < 3072; idx += 256) {
        int q = idx & 127, up = idx >> 7;
        int xy = t * 128 + q, x = xy >> 6, y = xy & 63;
        unsigned int wv = *(const unsigned int*)(PH + ((size_t)(f * 48 + x) * 512 + bn * 64 + y) * 48 + up * 2);
        phl[(up * 2) * 132 + q] = b2f((unsigned short)(wv & 0xffffu));
        phl[(up * 2 + 1) * 132 + q] = b2f((unsigned short)(wv >> 16));
    }
    // A-cache: pw rows for this lane's 4 m-fragments, both k-halves
    bf16x8 a[4][2];
#pragma unroll
    for (int m = 0; m < 4; ++m) {
        int q = wm * 64 + m * 16 + lr;
        int xy = t * 128 + q, x = xy >> 6, y = xy & 63;
        const unsigned short* pwr = PW + ((size_t)(f * 64 + y) * 384 + bn * 48 + x) * 64;
        a[m][0] = *(const bf16x8*)(pwr + lk8);
        a[m][1] = *(const bf16x8*)(pwr + 32 + lk8);
    }
    __syncthreads();

    // per-lane V base: d-row = dh*64 + wn*32 + n*16 + lr, key chunk = kt*32 + lk8
    const unsigned short* vsrc = Vt + (size_t)(fb * 4 + nh) * 128 * HWSZ;
    const unsigned short* vrow[2];
#pragma unroll
    for (int n = 0; n < 2; ++n)
        vrow[n] = vsrc + (size_t)(dh * 64 + wn * 32 + n * 16 + lr) * HWSZ + lk8;

    // prologue: preload kt=0 -> setA, kt=1 -> setB
    bf16x8 bvA[2], bvB[2];
#pragma unroll
    for (int n = 0; n < 2; ++n) bvA[n] = *(const bf16x8*)(vrow[n] + 0 * 32);
#pragma unroll
    for (int n = 0; n < 2; ++n) bvB[n] = *(const bf16x8*)(vrow[n] + 1 * 32);

    f32x4 out_acc[4][2] = {};
    const f32x4 zero4 = {0.f, 0.f, 0.f, 0.f};
    for (int u = 0; u < 48; ++u) {
        f32x4 phv[4];
#pragma unroll
        for (int m = 0; m < 4; ++m)
            phv[m] = *(const f32x4*)&phl[u * 132 + wm * 64 + m * 16 + lg * 4];
        f32x4 Y[4][2];
        // ks = 0: consume setA (kt = 2u), then refill setA with kt = 2u+2
        {
#pragma unroll
            for (int m = 0; m < 4; ++m)
#pragma unroll
                for (int n = 0; n < 2; ++n)
                    Y[m][n] = __builtin_amdgcn_mfma_f32_16x16x32_bf16(a[m][0], bvA[n], zero4, 0, 0, 0);
            int ktn = 2 * u + 2; if (ktn > 95) ktn = 95;
#pragma unroll
            for (int n = 0; n < 2; ++n) bvA[n] = *(const bf16x8*)(vrow[n] + (size_t)ktn * 32);
        }
        // ks = 1: consume setB (kt = 2u+1), then refill setB with kt = 2u+3
        {
#pragma unroll
            for (int m = 0; m < 4; ++m)
#pragma unroll
                for (int n = 0; n < 2; ++n)
                    Y[m][n] = __builtin_amdgcn_mfma_f32_16x16x32_bf16(a[m][1], bvB[n], Y[m][n], 0, 0, 0);
            int ktn = 2 * u + 3; if (ktn > 95) ktn = 95;
#pragma unroll
            for (int n = 0; n < 2; ++n) bvB[n] = *(const bf16x8*)(vrow[n] + (size_t)ktn * 32);
        }
#pragma unroll
        for (int m = 0; m < 4; ++m)
#pragma unroll
            for (int n = 0; n < 2; ++n)
                out_acc[m][n] += phv[m] * Y[m][n];
    }
    unsigned short* aobase = AO + (size_t)fb * HWSZ * 512 + nh * 128;
#pragma unroll
    for (int m = 0; m < 4; ++m)
#pragma unroll
        for (int n = 0; n < 2; ++n) {
            int dcol = dh * 64 + wn * 32 + n * 16 + lr;
            int r0 = wm * 64 + m * 16 + lg * 4;
#pragma unroll
            for (int r = 0; r < 4; ++r) {
                int xy = t * 128 + r0 + r;
                aobase[(size_t)xy * 512 + dcol] = f2b(out_acc[m][n][r]);
            }
        }
}

// ---------------- K4: out = fmap + gamma * (AO @ Wp^T) ----------------
__global__ __launch_bounds__(256) void k_proj(const unsigned short* __restrict__ AO,
                                              const unsigned short* __restrict__ Wpb,
                                              const float* __restrict__ f0,
                                              const float* __restrict__ f1,
                                              const float* __restrict__ gamma,
                                              float* __restrict__ out) {
    __shared__ unsigned short Asub[64 * 136];
    __shared__ unsigned short Bsub[128 * 136];
    int t = blockIdx.x, fb = blockIdx.y;
    int f = fb >> 1, bb = fb & 1;
    int tid = threadIdx.x;
    int l = tid & 63, w = tid >> 6;
    int wm = w >> 1, wn = w & 1;
    int lr = l & 15, lk8 = (l >> 4) * 8;
    f32x4 acc[2][4] = {};
    for (int ks = 0; ks < 4; ++ks) {
        if (ks) __syncthreads();
        for (int ch = tid; ch < 1024; ch += 256) {
            int row = ch >> 4, seg = ch & 15;
            *(bf16x8*)&Asub[row * 136 + seg * 8] =
                *(const bf16x8*)(AO + (size_t)(fb * HWSZ + t * 64 + row) * 512 + ks * 128 + seg * 8);
        }
        for (int ch = tid; ch < 2048; ch += 256) {
            int row = ch >> 4, seg = ch & 15;
            *(bf16x8*)&Bsub[row * 136 + seg * 8] =
                *(const bf16x8*)(Wpb + (size_t)row * 512 + ks * 128 + seg * 8);
        }
        __syncthreads();
#pragma unroll
        for (int kt = 0; kt < 4; ++kt) {
            bf16x8 a[2], b[4];
#pragma unroll
            for (int m = 0; m < 2; ++m)
                a[m] = *(const bf16x8*)&Asub[(wm * 32 + m * 16 + lr) * 136 + kt * 32 + lk8];
#pragma unroll
            for (int n = 0; n < 4; ++n)
                b[n] = *(const bf16x8*)&Bsub[(wn * 64 + n * 16 + lr) * 136 + kt * 32 + lk8];
#pragma unroll
            for (int m = 0; m < 2; ++m)
#pragma unroll
                for (int n = 0; n < 4; ++n)
                    acc[m][n] = __builtin_amdgcn_mfma_f32_16x16x32_bf16(a[m], b[n], acc[m][n], 0, 0, 0);
        }
    }
    const float* fmapf = f ? f1 : f0;
    float g = gamma[0];
#pragma unroll
    for (int m = 0; m < 2; ++m)
#pragma unroll
        for (int n = 0; n < 4; ++n) {
            int c = wn * 64 + n * 16 + lr;
            int pos0 = t * 64 + wm * 32 + m * 16 + (l >> 4) * 4;
            size_t addr = (size_t)(bb * 128 + c) * HWSZ + pos0;
            float4 fv = *(const float4*)(fmapf + addr);
            float4 ov;
            ov.x = fv.x + g * acc[m][n][0];
            ov.y = fv.y + g * acc[m][n][1];
            ov.z = fv.z + g * acc[m][n][2];
            ov.w = fv.w + g * acc[m][n][3];
            *(float4*)(out + (size_t)f * 786432 + addr) = ov;
        }
}

extern "C" void kernel_launch(void* const* d_in, const int* in_sizes, int n_in,
                              void* d_out, int out_size, void* d_ws, size_t ws_size,
                              hipStream_t stream) {
    (void)in_sizes; (void)n_in; (void)out_size; (void)ws_size;
    const float* fmap1 = (const float*)d_in[0];
    const float* fmap2 = (const float*)d_in[1];
    const float* Wqk   = (const float*)d_in[2];
    const float* Wv    = (const float*)d_in[3];
    const float* rel_h = (const float*)d_in[4];
    const float* rel_w = (const float*)d_in[5];
    const float* Wp    = (const float*)d_in[6];
    const float* gamma = (const float*)d_in[7];
    float* out = (float*)d_out;
    char* ws = (char*)d_ws;

    unsigned short* Xb   = (unsigned short*)(ws + 0);
    unsigned short* Wcat = (unsigned short*)(ws + 3145728);
    unsigned short* Wpb  = (unsigned short*)(ws + 3407872);
    unsigned short* Qx   = (unsigned short*)(ws + 3538944);
    unsigned short* AO   = Qx;                               // alias: Qx dead after K2
    unsigned short* Vt   = (unsigned short*)(ws + 16121856);
    unsigned short* PH   = (unsigned short*)(ws + 28704768);
    unsigned short* PW   = (unsigned short*)(ws + 33423360);

    k_transpose<<<dim3(96, 4, 4), dim3(32, 8), 0, stream>>>(fmap1, fmap2, Xb);
    k_weights<<<dim3(768), dim3(256), 0, stream>>>(Wqk, Wv, Wp, Wcat, Wpb);
    k_qv<<<dim3(48, 8, 4), dim3(256), 0, stream>>>(Xb, Wcat, Qx, Vt);
    k_ph<<<dim3(48, 2), dim3(256), 0, stream>>>(Qx, rel_h, PH);
    k_pw<<<dim3(64, 2), dim3(256), 0, stream>>>(Qx, rel_w, PW);
    k_attn<<<dim3(768), dim3(256), 0, stream>>>(PH, PW, Vt, AO);
    k_proj<<<dim3(48, 4), dim3(256), 0, stream>>>(AO, Wpb, fmap1, fmap2, gamma, out);
}

// Round 7
// 137.621 us; speedup vs baseline: 1.2989x; 1.1295x over previous
//
#include <hip/hip_runtime.h>
#include <cstdint>
#include <cstddef>

typedef short bf16x8 __attribute__((ext_vector_type(8)));
typedef float f32x4 __attribute__((ext_vector_type(4)));

#define HH 48
#define WW 64
#define HWSZ 3072
#define SCALE_Q 0.08838834764831845f

__device__ __forceinline__ float b2f(unsigned short u) {
    union { unsigned int i; float f; } c; c.i = ((unsigned int)u) << 16; return c.f;
}
__device__ __forceinline__ unsigned short f2b(float f) {
    union { float f; unsigned int i; } c; c.f = f;
    unsigned int r = (c.i + 0x7fffu + ((c.i >> 16) & 1u)) >> 16;
    return (unsigned short)r;
}

// ---------------- K0a: fmap (fb, c, pos) f32 -> Xb (fb, pos, c) bf16 ----------------
__global__ __launch_bounds__(256) void k_transpose(const float* __restrict__ f0,
                                                   const float* __restrict__ f1,
                                                   unsigned short* __restrict__ Xb) {
    __shared__ float t[32][33];
    int fb = blockIdx.z; int f = fb >> 1, bb = fb & 1;
    const float* src = f ? f1 : f0;
    int pT = blockIdx.x * 32, cT = blockIdx.y * 32;
    int tx = threadIdx.x, ty = threadIdx.y;
#pragma unroll
    for (int i = 0; i < 4; ++i) {
        int c = cT + ty + i * 8, pos = pT + tx;
        t[ty + i * 8][tx] = src[(size_t)(bb * 128 + c) * HWSZ + pos];
    }
    __syncthreads();
#pragma unroll
    for (int i = 0; i < 4; ++i) {
        int pos = pT + ty + i * 8, c = cT + tx;
        Xb[(size_t)(fb * HWSZ + pos) * 128 + c] = f2b(t[tx][ty + i * 8]);
    }
}

// ---------------- K0b: weights -> bf16 ----------------
__global__ __launch_bounds__(256) void k_weights(const float* __restrict__ Wqk,
                                                 const float* __restrict__ Wv,
                                                 const float* __restrict__ Wp,
                                                 unsigned short* __restrict__ Wcat,
                                                 unsigned short* __restrict__ Wpb) {
    int idx = blockIdx.x * 256 + threadIdx.x;
    if (idx < 131072) {
        int o = idx >> 7, c = idx & 127;
        float v = (o < 512) ? Wqk[o * 128 + c] * SCALE_Q : Wv[(o - 512) * 128 + c];
        Wcat[idx] = f2b(v);
    } else {
        int j = idx - 131072;
        Wpb[j] = f2b(Wp[j]);
    }
}

// ---------------- K1: q/v projections ----------------
__global__ __launch_bounds__(256) void k_qv(const unsigned short* __restrict__ Xb,
                                            const unsigned short* __restrict__ Wcat,
                                            unsigned short* __restrict__ Qx,
                                            unsigned short* __restrict__ Vt) {
    __shared__ unsigned short Asub[64 * 136];
    __shared__ unsigned short Bsub[128 * 136];
    int mt = blockIdx.x, nt = blockIdx.y, fb = blockIdx.z;
    int tid = threadIdx.x;
    const unsigned short* asrc = Xb + (size_t)(fb * HWSZ + mt * 64) * 128;
    const unsigned short* bsrc = Wcat + (size_t)nt * 128 * 128;
    for (int ch = tid; ch < 1024; ch += 256) {
        int row = ch >> 4, seg = ch & 15;
        *(bf16x8*)&Asub[row * 136 + seg * 8] = *(const bf16x8*)(asrc + ch * 8);
    }
    for (int ch = tid; ch < 2048; ch += 256) {
        int row = ch >> 4, seg = ch & 15;
        *(bf16x8*)&Bsub[row * 136 + seg * 8] = *(const bf16x8*)(bsrc + ch * 8);
    }
    __syncthreads();
    int l = tid & 63, w = tid >> 6;
    int wm = w >> 1, wn = w & 1;
    int lr = l & 15, lk8 = (l >> 4) * 8;
    f32x4 acc[2][4] = {};
#pragma unroll
    for (int kt = 0; kt < 4; ++kt) {
        bf16x8 a[2], b[4];
#pragma unroll
        for (int m = 0; m < 2; ++m)
            a[m] = *(const bf16x8*)&Asub[(wm * 32 + m * 16 + lr) * 136 + kt * 32 + lk8];
#pragma unroll
        for (int n = 0; n < 4; ++n)
            b[n] = *(const bf16x8*)&Bsub[(wn * 64 + n * 16 + lr) * 136 + kt * 32 + lk8];
#pragma unroll
        for (int m = 0; m < 2; ++m)
#pragma unroll
            for (int n = 0; n < 4; ++n)
                acc[m][n] = __builtin_amdgcn_mfma_f32_16x16x32_bf16(a[m], b[n], acc[m][n], 0, 0, 0);
    }
    int f = fb >> 1, bb = fb & 1;
#pragma unroll
    for (int m = 0; m < 2; ++m)
#pragma unroll
        for (int n = 0; n < 4; ++n) {
            int o = nt * 128 + wn * 64 + n * 16 + lr;
            int pos0 = mt * 64 + wm * 32 + m * 16 + (l >> 4) * 4;
            if (o < 512) {
                int nh = o >> 7, d = o & 127;
#pragma unroll
                for (int r = 0; r < 4; ++r) {
                    int pos = pos0 + r, x = pos >> 6, y = pos & 63;
                    Qx[(size_t)((f * 48 + x) * 512 + (bb * 4 + nh) * 64 + y) * 128 + d] = f2b(acc[m][n][r]);
                }
            } else {
                int oo = o - 512, nh = oo >> 7, d = oo & 127;
                uint2 val;
                val.x = (unsigned int)f2b(acc[m][n][0]) | ((unsigned int)f2b(acc[m][n][1]) << 16);
                val.y = (unsigned int)f2b(acc[m][n][2]) | ((unsigned int)f2b(acc[m][n][3]) << 16);
                *(uint2*)&Vt[(size_t)((fb * 4 + nh) * 128 + d) * HWSZ + pos0] = val;
            }
        }
}

// ---------------- K2a: ph softmax over u ----------------
__global__ __launch_bounds__(256) void k_ph(const unsigned short* __restrict__ Qx,
                                            const float* __restrict__ rel_h,
                                            unsigned short* __restrict__ PH) {
    __shared__ float sm[4][16][52];
    int x = blockIdx.x, f = blockIdx.y;
    int tid = threadIdx.x, l = tid & 63, w = tid >> 6;
    int lr = l & 15, lk8 = (l >> 4) * 8;
    bf16x8 bh[3][4];
#pragma unroll
    for (int ut = 0; ut < 3; ++ut) {
        int u = ut * 16 + lr, rr = x - u + 99;
#pragma unroll
        for (int kt = 0; kt < 4; ++kt) {
            const float* s = rel_h + rr * 128 + kt * 32 + lk8;
            float4 a0 = *(const float4*)s, a1 = *(const float4*)(s + 4);
            bf16x8 pk;
            pk[0] = (short)f2b(a0.x); pk[1] = (short)f2b(a0.y); pk[2] = (short)f2b(a0.z); pk[3] = (short)f2b(a0.w);
            pk[4] = (short)f2b(a1.x); pk[5] = (short)f2b(a1.y); pk[6] = (short)f2b(a1.z); pk[7] = (short)f2b(a1.w);
            bh[ut][kt] = pk;
        }
    }
    const unsigned short* qbase = Qx + (size_t)(f * 48 + x) * 512 * 128;
    unsigned short* phbase = PH + (size_t)(f * 48 + x) * 512 * 48;
    for (int mt = 0; mt < 8; ++mt) {
        int rg = w * 128 + mt * 16 + lr;
        const unsigned short* qrow = qbase + (size_t)rg * 128;
        bf16x8 a[4];
#pragma unroll
        for (int kt = 0; kt < 4; ++kt) a[kt] = *(const bf16x8*)(qrow + kt * 32 + lk8);
        f32x4 acc[3] = {};
#pragma unroll
        for (int kt = 0; kt < 4; ++kt)
#pragma unroll
            for (int ut = 0; ut < 3; ++ut)
                acc[ut] = __builtin_amdgcn_mfma_f32_16x16x32_bf16(a[kt], bh[ut][kt], acc[ut], 0, 0, 0);
        __syncthreads();
#pragma unroll
        for (int ut = 0; ut < 3; ++ut)
#pragma unroll
            for (int r = 0; r < 4; ++r)
                sm[w][(l >> 4) * 4 + r][ut * 16 + lr] = acc[ut][r];
        __syncthreads();
        int part = l >> 4;
        float vb[12];
        float mx = -1e30f;
#pragma unroll
        for (int j = 0; j < 12; ++j) { vb[j] = sm[w][lr][part * 12 + j]; mx = fmaxf(mx, vb[j]); }
        mx = fmaxf(mx, __shfl_xor(mx, 16, 64));
        mx = fmaxf(mx, __shfl_xor(mx, 32, 64));
        float ssum = 0.f;
#pragma unroll
        for (int j = 0; j < 12; ++j) { vb[j] = __expf(vb[j] - mx); ssum += vb[j]; }
        ssum += __shfl_xor(ssum, 16, 64);
        ssum += __shfl_xor(ssum, 32, 64);
        float inv = 1.0f / ssum;
        unsigned short* dst = phbase + (size_t)(w * 128 + mt * 16 + lr) * 48 + part * 12;
#pragma unroll
        for (int j = 0; j < 12; ++j) dst[j] = f2b(vb[j] * inv);
    }
}

// ---------------- K2b: pw softmax over v ----------------
__global__ __launch_bounds__(256) void k_pw(const unsigned short* __restrict__ Qx,
                                            const float* __restrict__ rel_w,
                                            unsigned short* __restrict__ PW) {
    __shared__ float sm[4][16][68];
    int y = blockIdx.x, f = blockIdx.y;
    int tid = threadIdx.x, l = tid & 63, w = tid >> 6;
    int lr = l & 15, lk8 = (l >> 4) * 8;
    bf16x8 bw[4][4];
#pragma unroll
    for (int vt = 0; vt < 4; ++vt) {
        int v = vt * 16 + lr, rr = y - v + 99;
#pragma unroll
        for (int kt = 0; kt < 4; ++kt) {
            const float* s = rel_w + rr * 128 + kt * 32 + lk8;
            float4 a0 = *(const float4*)s, a1 = *(const float4*)(s + 4);
            bf16x8 pk;
            pk[0] = (short)f2b(a0.x); pk[1] = (short)f2b(a0.y); pk[2] = (short)f2b(a0.z); pk[3] = (short)f2b(a0.w);
            pk[4] = (short)f2b(a1.x); pk[5] = (short)f2b(a1.y); pk[6] = (short)f2b(a1.z); pk[7] = (short)f2b(a1.w);
            bw[vt][kt] = pk;
        }
    }
    for (int mt = 0; mt < 6; ++mt) {
        int rg = w * 96 + mt * 16 + lr;
        int bn = rg / 48, xx = rg - bn * 48;
        const unsigned short* qrow = Qx + (size_t)((f * 48 + xx) * 512 + bn * 64 + y) * 128;
        bf16x8 a[4];
#pragma unroll
        for (int kt = 0; kt < 4; ++kt) a[kt] = *(const bf16x8*)(qrow + kt * 32 + lk8);
        f32x4 acc[4] = {};
#pragma unroll
        for (int kt = 0; kt < 4; ++kt)
#pragma unroll
            for (int vt = 0; vt < 4; ++vt)
                acc[vt] = __builtin_amdgcn_mfma_f32_16x16x32_bf16(a[kt], bw[vt][kt], acc[vt], 0, 0, 0);
        __syncthreads();
#pragma unroll
        for (int vt = 0; vt < 4; ++vt)
#pragma unroll
            for (int r = 0; r < 4; ++r)
                sm[w][(l >> 4) * 4 + r][vt * 16 + lr] = acc[vt][r];
        __syncthreads();
        int part = l >> 4;
        float vb[16];
        float mx = -1e30f;
#pragma unroll
        for (int j = 0; j < 16; ++j) { vb[j] = sm[w][lr][part * 16 + j]; mx = fmaxf(mx, vb[j]); }
        mx = fmaxf(mx, __shfl_xor(mx, 16, 64));
        mx = fmaxf(mx, __shfl_xor(mx, 32, 64));
        float ssum = 0.f;
#pragma unroll
        for (int j = 0; j < 16; ++j) { vb[j] = __expf(vb[j] - mx); ssum += vb[j]; }
        ssum += __shfl_xor(ssum, 16, 64);
        ssum += __shfl_xor(ssum, 32, 64);
        float inv = 1.0f / ssum;
        unsigned short* dst = PW + (size_t)((f * 64 + y) * 384 + rg) * 64 + part * 16;
#pragma unroll
        for (int j = 0; j < 16; ++j) dst[j] = f2b(vb[j] * inv);
    }
}

// ---------------- K3 v3: LDS-staged coalesced V, single-barrier double-buffer ----------------
// Grid 1024 = (32 q-tiles x 2 d-halves) x 16 fbn; 512 threads (8 waves = 2 qm x 4 wn).
// Per step u: V-tile 64 keys x 64 d staged coalesced (reg->LDS, XOR-swizzled), one barrier.
__global__ __launch_bounds__(512, 4) void k_attn(const unsigned short* __restrict__ PH,
                                                 const unsigned short* __restrict__ PW,
                                                 const unsigned short* __restrict__ Vt,
                                                 unsigned short* __restrict__ AO) {
    __shared__ float phl[48 * 96];                 // [u][q] f32, broadcast reads (18432 B)
    __shared__ unsigned short vbuf[2][64 * 64];    // [d][key-chunk swizzled] (2 x 8192 B)
    int bid = blockIdx.x;
    int r16 = bid & 15;
    int rest = bid >> 4;                            // 0..63
    int t = rest >> 1, dh = rest & 1;               // q-tile (96 rows), d-half
    int fbn = (r16 & 7) * 2 + (r16 >> 3);           // XCD-local V reuse
    int f = fbn >> 3, bidx = (fbn >> 2) & 1, nh = fbn & 3;
    int fb = f * 2 + bidx, bn = bidx * 4 + nh;
    int tid = threadIdx.x;
    int l = tid & 63, w = tid >> 6;
    int qm = w >> 2, wn = w & 3;                    // qm 0..1 (48 q), wn 0..3 (16 d)
    int lr = l & 15, lg = l >> 4, lk8 = lg * 8;

    // stage ph transposed [u][q] as f32
    for (int i = tid; i < 96 * 24; i += 512) {
        int q = i / 24, up = i - q * 24;
        int xy = t * 96 + q, x = xy >> 6, y = xy & 63;
        unsigned int wv = *(const unsigned int*)(PH + ((size_t)(f * 48 + x) * 512 + bn * 64 + y) * 48 + up * 2);
        phl[(up * 2) * 96 + q]     = b2f((unsigned short)(wv & 0xffffu));
        phl[(up * 2 + 1) * 96 + q] = b2f((unsigned short)(wv >> 16));
    }
    // pw A-fragments (3 m-frags x 2 k-halves) in registers
    bf16x8 a[3][2];
#pragma unroll
    for (int m = 0; m < 3; ++m) {
        int xy = t * 96 + qm * 48 + m * 16 + lr;
        int x = xy >> 6, y = xy & 63;
        const unsigned short* pwr = PW + ((size_t)(f * 64 + y) * 384 + bn * 48 + x) * 64;
        a[m][0] = *(const bf16x8*)(pwr + lk8);
        a[m][1] = *(const bf16x8*)(pwr + 32 + lk8);
    }
    // V staging: thread -> (d-row, chunk); coalesced global read, swizzled LDS write
    const unsigned short* vsrc = Vt + (size_t)((fb * 4 + nh) * 128 + dh * 64) * HWSZ;
    int sd = tid >> 3, sch = tid & 7;
    const unsigned short* vsrow = vsrc + (size_t)sd * HWSZ + sch * 8;
    int vdoff = sd * 64 + ((sch ^ (sd & 7)) * 8);
    {
        bf16x8 r0 = *(const bf16x8*)vsrow;          // u = 0 tile
        *(bf16x8*)&vbuf[0][vdoff] = r0;
    }
    __syncthreads();

    // B-fragment LDS offsets (swizzled): row = wn*16+lr, slot = (ks*4+lg) ^ (row&7)
    int rrow = wn * 16 + lr;
    int bo0 = rrow * 64 + ((lg ^ (rrow & 7)) * 8);
    int bo1 = rrow * 64 + (((4 + lg) ^ (rrow & 7)) * 8);
    int phbase = qm * 48 + lg * 4;
    f32x4 out_acc[3] = {};
    const f32x4 zero4 = {0.f, 0.f, 0.f, 0.f};
    int cur = 0;
    for (int u = 0; u < 48; ++u) {
        bf16x8 r;
        if (u < 47) r = *(const bf16x8*)(vsrow + (size_t)(u + 1) * 64);   // issue early
        bf16x8 b0 = *(const bf16x8*)&vbuf[cur][bo0];
        bf16x8 b1 = *(const bf16x8*)&vbuf[cur][bo1];
        f32x4 phv[3];
#pragma unroll
        for (int m = 0; m < 3; ++m)
            phv[m] = *(const f32x4*)&phl[u * 96 + phbase + m * 16];
        f32x4 Y[3];
#pragma unroll
        for (int m = 0; m < 3; ++m)
            Y[m] = __builtin_amdgcn_mfma_f32_16x16x32_bf16(a[m][0], b0, zero4, 0, 0, 0);
#pragma unroll
        for (int m = 0; m < 3; ++m)
            Y[m] = __builtin_amdgcn_mfma_f32_16x16x32_bf16(a[m][1], b1, Y[m], 0, 0, 0);
#pragma unroll
        for (int m = 0; m < 3; ++m)
            out_acc[m] += phv[m] * Y[m];
        if (u < 47) *(bf16x8*)&vbuf[cur ^ 1][vdoff] = r;                   // write late
        __syncthreads();
        cur ^= 1;
    }
    unsigned short* aobase = AO + (size_t)fb * HWSZ * 512 + nh * 128;
    int dcol = dh * 64 + rrow;
#pragma unroll
    for (int m = 0; m < 3; ++m) {
        int r0 = t * 96 + qm * 48 + m * 16 + lg * 4;
#pragma unroll
        for (int r = 0; r < 4; ++r)
            aobase[(size_t)(r0 + r) * 512 + dcol] = f2b(out_acc[m][r]);
    }
}

// ---------------- K4: out = fmap + gamma * (AO @ Wp^T) ----------------
__global__ __launch_bounds__(256) void k_proj(const unsigned short* __restrict__ AO,
                                              const unsigned short* __restrict__ Wpb,
                                              const float* __restrict__ f0,
                                              const float* __restrict__ f1,
                                              const float* __restrict__ gamma,
                                              float* __restrict__ out) {
    __shared__ unsigned short Asub[64 * 136];
    __shared__ unsigned short Bsub[128 * 136];
    int t = blockIdx.x, fb = blockIdx.y;
    int f = fb >> 1, bb = fb & 1;
    int tid = threadIdx.x;
    int l = tid & 63, w = tid >> 6;
    int wm = w >> 1, wn = w & 1;
    int lr = l & 15, lk8 = (l >> 4) * 8;
    f32x4 acc[2][4] = {};
    for (int ks = 0; ks < 4; ++ks) {
        if (ks) __syncthreads();
        for (int ch = tid; ch < 1024; ch += 256) {
            int row = ch >> 4, seg = ch & 15;
            *(bf16x8*)&Asub[row * 136 + seg * 8] =
                *(const bf16x8*)(AO + (size_t)(fb * HWSZ + t * 64 + row) * 512 + ks * 128 + seg * 8);
        }
        for (int ch = tid; ch < 2048; ch += 256) {
            int row = ch >> 4, seg = ch & 15;
            *(bf16x8*)&Bsub[row * 136 + seg * 8] =
                *(const bf16x8*)(Wpb + (size_t)row * 512 + ks * 128 + seg * 8);
        }
        __syncthreads();
#pragma unroll
        for (int kt = 0; kt < 4; ++kt) {
            bf16x8 a[2], b[4];
#pragma unroll
            for (int m = 0; m < 2; ++m)
                a[m] = *(const bf16x8*)&Asub[(wm * 32 + m * 16 + lr) * 136 + kt * 32 + lk8];
#pragma unroll
            for (int n = 0; n < 4; ++n)
                b[n] = *(const bf16x8*)&Bsub[(wn * 64 + n * 16 + lr) * 136 + kt * 32 + lk8];
#pragma unroll
            for (int m = 0; m < 2; ++m)
#pragma unroll
                for (int n = 0; n < 4; ++n)
                    acc[m][n] = __builtin_amdgcn_mfma_f32_16x16x32_bf16(a[m], b[n], acc[m][n], 0, 0, 0);
        }
    }
    const float* fmapf = f ? f1 : f0;
    float g = gamma[0];
#pragma unroll
    for (int m = 0; m < 2; ++m)
#pragma unroll
        for (int n = 0; n < 4; ++n) {
            int c = wn * 64 + n * 16 + lr;
            int pos0 = t * 64 + wm * 32 + m * 16 + (l >> 4) * 4;
            size_t addr = (size_t)(bb * 128 + c) * HWSZ + pos0;
            float4 fv = *(const float4*)(fmapf + addr);
            float4 ov;
            ov.x = fv.x + g * acc[m][n][0];
            ov.y = fv.y + g * acc[m][n][1];
            ov.z = fv.z + g * acc[m][n][2];
            ov.w = fv.w + g * acc[m][n][3];
            *(float4*)(out + (size_t)f * 786432 + addr) = ov;
        }
}

extern "C" void kernel_launch(void* const* d_in, const int* in_sizes, int n_in,
                              void* d_out, int out_size, void* d_ws, size_t ws_size,
                              hipStream_t stream) {
    (void)in_sizes; (void)n_in; (void)out_size; (void)ws_size;
    const float* fmap1 = (const float*)d_in[0];
    const float* fmap2 = (const float*)d_in[1];
    const float* Wqk   = (const float*)d_in[2];
    const float* Wv    = (const float*)d_in[3];
    const float* rel_h = (const float*)d_in[4];
    const float* rel_w = (const float*)d_in[5];
    const float* Wp    = (const float*)d_in[6];
    const float* gamma = (const float*)d_in[7];
    float* out = (float*)d_out;
    char* ws = (char*)d_ws;

    unsigned short* Xb   = (unsigned short*)(ws + 0);
    unsigned short* Wcat = (unsigned short*)(ws + 3145728);
    unsigned short* Wpb  = (unsigned short*)(ws + 3407872);
    unsigned short* Qx   = (unsigned short*)(ws + 3538944);
    unsigned short* AO   = Qx;                               // alias: Qx dead after K2
    unsigned short* Vt   = (unsigned short*)(ws + 16121856);
    unsigned short* PH   = (unsigned short*)(ws + 28704768);
    unsigned short* PW   = (unsigned short*)(ws + 33423360);

    k_transpose<<<dim3(96, 4, 4), dim3(32, 8), 0, stream>>>(fmap1, fmap2, Xb);
    k_weights<<<dim3(768), dim3(256), 0, stream>>>(Wqk, Wv, Wp, Wcat, Wpb);
    k_qv<<<dim3(48, 8, 4), dim3(256), 0, stream>>>(Xb, Wcat, Qx, Vt);
    k_ph<<<dim3(48, 2), dim3(256), 0, stream>>>(Qx, rel_h, PH);
    k_pw<<<dim3(64, 2), dim3(256), 0, stream>>>(Qx, rel_w, PW);
    k_attn<<<dim3(1024), dim3(512), 0, stream>>>(PH, PW, Vt, AO);
    k_proj<<<dim3(48, 4), dim3(256), 0, stream>>>(AO, Wpb, fmap1, fmap2, gamma, out);
}